// Round 1
// baseline (64123.804 us; speedup 1.0000x reference)
//
#include <hip/hip_runtime.h>
#include <stdint.h>
#include <math.h>

// ====================== problem constants ======================
#define NNODE 256
#define BATCH 32
#define TLEN  128
#define ENC_H 64
#define DEC_HID 96
#define ENC_C 65   // IN_DIM + ENC_H
#define DEC_C 97   // OUT_DIM + DEC_HID
#define ROWS  8192 // NNODE*BATCH

// JAX >= 0.5 defaults jax_threefry_partitionable=True. If absmax ~0.05-0.5,
// flip this to 0 (legacy threefry counter layout) next round.
#ifndef PRNG_PARTITIONABLE
#define PRNG_PARTITIONABLE 1
#endif

// ====================== Threefry-2x32 (20 rounds) ======================
__host__ __device__ inline uint32_t rotl32_(uint32_t v, int d) {
  return (v << d) | (v >> (32 - d));
}

__host__ __device__ inline void tf2x32(uint32_t k0, uint32_t k1, uint32_t x0,
                                       uint32_t x1, uint32_t* o0, uint32_t* o1) {
  uint32_t ks2 = k0 ^ k1 ^ 0x1BD11BDAu;
  x0 += k0; x1 += k1;
  // G1 (13,15,26,6)
  x0 += x1; x1 = rotl32_(x1, 13); x1 ^= x0;
  x0 += x1; x1 = rotl32_(x1, 15); x1 ^= x0;
  x0 += x1; x1 = rotl32_(x1, 26); x1 ^= x0;
  x0 += x1; x1 = rotl32_(x1, 6);  x1 ^= x0;
  x0 += k1; x1 += ks2 + 1u;
  // G2 (17,29,16,24)
  x0 += x1; x1 = rotl32_(x1, 17); x1 ^= x0;
  x0 += x1; x1 = rotl32_(x1, 29); x1 ^= x0;
  x0 += x1; x1 = rotl32_(x1, 16); x1 ^= x0;
  x0 += x1; x1 = rotl32_(x1, 24); x1 ^= x0;
  x0 += ks2; x1 += k0 + 2u;
  // G3
  x0 += x1; x1 = rotl32_(x1, 13); x1 ^= x0;
  x0 += x1; x1 = rotl32_(x1, 15); x1 ^= x0;
  x0 += x1; x1 = rotl32_(x1, 26); x1 ^= x0;
  x0 += x1; x1 = rotl32_(x1, 6);  x1 ^= x0;
  x0 += k0; x1 += k1 + 3u;
  // G4
  x0 += x1; x1 = rotl32_(x1, 17); x1 ^= x0;
  x0 += x1; x1 = rotl32_(x1, 29); x1 ^= x0;
  x0 += x1; x1 = rotl32_(x1, 16); x1 ^= x0;
  x0 += x1; x1 = rotl32_(x1, 24); x1 ^= x0;
  x0 += k1; x1 += ks2 + 4u;
  // G5
  x0 += x1; x1 = rotl32_(x1, 13); x1 ^= x0;
  x0 += x1; x1 = rotl32_(x1, 15); x1 ^= x0;
  x0 += x1; x1 = rotl32_(x1, 26); x1 ^= x0;
  x0 += x1; x1 = rotl32_(x1, 6);  x1 ^= x0;
  x0 += ks2; x1 += k0 + 5u;
  *o0 = x0; *o1 = x1;
}

// jax.random.gumbel bit-faithful: uniform = bitcast((bits>>9)|0x3f800000)-1,
// u = max(tiny, f*(1-tiny)+tiny) [=f+tiny in f32]; g = -log(-log(u))
__device__ inline float gumbel_at(uint32_t k0, uint32_t k1, uint32_t idx) {
  uint32_t b, o0, o1;
#if PRNG_PARTITIONABLE
  tf2x32(k0, k1, 0u, idx, &o0, &o1);
  b = o0 ^ o1;
#else
  if (idx < 65536u) { tf2x32(k0, k1, idx, idx + 65536u, &o0, &o1); b = o0; }
  else              { tf2x32(k0, k1, idx - 65536u, idx, &o0, &o1); b = o1; }
#endif
  float f = __uint_as_float((b >> 9) | 0x3f800000u) - 1.0f;
  const float tiny = 1.17549435e-38f;
  float u = fmaxf(tiny, f + tiny);
  return -logf(-logf(u));
}

// ====================== setup kernels ======================
// e1 = We1 @ Memory, e2 = We2 @ Memory, row norms
__global__ __launch_bounds__(256) void setup_embed_kernel(
    const float* __restrict__ We1, const float* __restrict__ We2,
    const float* __restrict__ Mem, float* __restrict__ e1, float* __restrict__ e2,
    float* __restrict__ n1, float* __restrict__ n2) {
  int n = threadIdx.x;
  float a[8];
  float s;
  for (int m = 0; m < 8; ++m) a[m] = We1[n * 8 + m];
  s = 0.f;
  for (int j = 0; j < 32; ++j) {
    float v = 0.f;
    for (int m = 0; m < 8; ++m) v = fmaf(a[m], Mem[m * 32 + j], v);
    e1[n * 32 + j] = v;
    s = fmaf(v, v, s);
  }
  n1[n] = sqrtf(s);
  for (int m = 0; m < 8; ++m) a[m] = We2[n * 8 + m];
  s = 0.f;
  for (int j = 0; j < 32; ++j) {
    float v = 0.f;
    for (int m = 0; m < 8; ++m) v = fmaf(a[m], Mem[m * 32 + j], v);
    e2[n * 32 + j] = v;
    s = fmaf(v, v, s);
  }
  n2[n] = sqrtf(s);
}

__global__ void stats_init_kernel(int* stats) {
  stats[0] = 0;           // max degree
  stats[1] = 0;           // has any edge
  stats[2] = 0x7fffffff;  // min degree
}

// adjacency via gumbel-argmax; row-degree; global L max/min stats
__global__ __launch_bounds__(256) void adj_kernel(
    const float* __restrict__ eA, const float* __restrict__ eB,
    const float* __restrict__ nA, const float* __restrict__ nB,
    uint32_t k0, uint32_t k1, float* __restrict__ adj, float* __restrict__ deg,
    int* __restrict__ stats) {
  int i = blockIdx.x, j = threadIdx.x;
  float dot = 0.f;
  for (int c = 0; c < 32; ++c) dot = fmaf(eA[i * 32 + c], eB[j * 32 + c], dot);
  float g = dot / (nA[i] * nB[j] + 1e-6f);
  g = (g + 1.0f) * 0.5f;
  uint32_t f = ((uint32_t)(i * 256 + j)) * 2u;
  float g0 = gumbel_at(k0, k1, f);
  float g1 = gumbel_at(k0, k1, f + 1u);
  // argmax over {g+g0, (1-g)+g1}; ties -> index 0
  float a = ((g + g0) >= ((1.0f - g) + g1)) ? 1.0f : 0.0f;
  if (i == j) a = 0.0f;
  adj[i * 256 + j] = a;
  __shared__ float red[256];
  red[j] = a;
  __syncthreads();
  for (int s = 128; s > 0; s >>= 1) {
    if (j < s) red[j] += red[j + s];
    __syncthreads();
  }
  if (j == 0) {
    float d = red[0];
    deg[i] = d;
    atomicMax(&stats[0], (int)d);
    atomicMin(&stats[2], (int)d);
    if (d > 0.5f) atomicOr(&stats[1], 1);
  }
}

// S1 = 2L/lam - I, L = diag(d) - adj, lam = L.max() - L.min()
__global__ __launch_bounds__(256) void lap_kernel(const float* __restrict__ adj,
                                                  const float* __restrict__ deg,
                                                  const int* __restrict__ stats,
                                                  float* __restrict__ S1) {
  int i = blockIdx.x, j = threadIdx.x;
  float lmax = (float)stats[0];                               // max over diag >= off-diag max
  float lmin = stats[1] ? -1.0f : (float)stats[2];            // any edge -> -1
  float lam = lmax - lmin;
  float L = (i == j) ? deg[i] : -adj[i * 256 + j];
  S1[i * 256 + j] = 2.0f * L / lam - ((i == j) ? 1.0f : 0.0f);
}

// T2 = 2*(S1@S1) - I  (scaling by 2 commutes exactly with fp ops)
__global__ __launch_bounds__(256) void t2_kernel(const float* __restrict__ A,
                                                 float* __restrict__ Cout) {
  __shared__ __align__(16) float sAT[32][68];
  __shared__ __align__(16) float sB[32][68];
  int tid = threadIdx.x;
  int tc = tid & 15, tr = tid >> 4;
  int row0 = blockIdx.y * 64, col0 = blockIdx.x * 64;
  float acc[4][4] = {};
  for (int m0 = 0; m0 < 256; m0 += 32) {
    for (int i = tid; i < 2048; i += 256) {
      int r = i >> 5, c = i & 31;
      sAT[c][r] = A[(size_t)(row0 + r) * 256 + m0 + c];
    }
    for (int i = tid; i < 2048; i += 256) {
      int r = i >> 6, c = i & 63;
      sB[r][c] = A[(size_t)(m0 + r) * 256 + col0 + c];
    }
    __syncthreads();
#pragma unroll
    for (int kk = 0; kk < 32; ++kk) {
      float4 av = *(const float4*)&sAT[kk][tr * 4];
      float4 bv = *(const float4*)&sB[kk][tc * 4];
      float a[4] = {av.x, av.y, av.z, av.w};
      float b[4] = {bv.x, bv.y, bv.z, bv.w};
#pragma unroll
      for (int i = 0; i < 4; ++i)
#pragma unroll
        for (int j = 0; j < 4; ++j) acc[i][j] = fmaf(a[i], b[j], acc[i][j]);
    }
    __syncthreads();
  }
#pragma unroll
  for (int i = 0; i < 4; ++i) {
    int row = row0 + tr * 4 + i;
#pragma unroll
    for (int j = 0; j < 4; ++j) {
      int col = col0 + tc * 4 + j;
      Cout[(size_t)row * 256 + col] = 2.0f * acc[i][j] - ((row == col) ? 1.0f : 0.0f);
    }
  }
}

// Fold Chebyshev-identity weight blocks (orig k=0 and k=3) into piece 0.
// Weff layout: (5*C, O); piece p>=1 maps to orig k = p + (p>=3)
__global__ void fold_w_kernel(const float* __restrict__ W, float* __restrict__ Weff,
                              int C, int O) {
  int idx = blockIdx.x * 256 + threadIdx.x;
  if (idx >= 5 * C * O) return;
  int o = idx % O;
  int rest = idx / O;
  int c = rest % C;
  int p = rest / C;
  float v;
  if (p == 0)
    v = W[(0 * C + c) * O + o] + W[(3 * C + c) * O + o];
  else {
    int korig = p + (p >= 3 ? 1 : 0);
    v = W[(korig * C + c) * O + o];
  }
  Weff[idx] = v;
}

// ====================== recurrent-step kernels ======================
// graph conv: Cout[k][n][b*C+c] = sum_m S_k[n][m] * V[m][b*C+c], k in 0..3
__global__ __launch_bounds__(256) void sconv_kernel(const float* __restrict__ Sall,
                                                    const float* __restrict__ V,
                                                    float* __restrict__ Cout, int NC) {
  __shared__ __align__(16) float sAT[32][68];
  __shared__ __align__(16) float sB[32][68];
  int tid = threadIdx.x;
  int tc = tid & 15, tr = tid >> 4;
  int k = blockIdx.z;
  const float* S = Sall + (size_t)k * (NNODE * NNODE);
  float* Ck = Cout + (size_t)k * NNODE * NC;
  int row0 = blockIdx.y * 64, col0 = blockIdx.x * 64;
  float acc[4][4] = {};
  for (int m0 = 0; m0 < NNODE; m0 += 32) {
    for (int i = tid; i < 2048; i += 256) {
      int r = i >> 5, c = i & 31;
      sAT[c][r] = S[(size_t)(row0 + r) * NNODE + m0 + c];
    }
    for (int i = tid; i < 2048; i += 256) {
      int r = i >> 6, c = i & 63;
      int col = col0 + c;
      sB[r][c] = (col < NC) ? V[(size_t)(m0 + r) * NC + col] : 0.0f;
    }
    __syncthreads();
#pragma unroll
    for (int kk = 0; kk < 32; ++kk) {
      float4 av = *(const float4*)&sAT[kk][tr * 4];
      float4 bv = *(const float4*)&sB[kk][tc * 4];
      float a[4] = {av.x, av.y, av.z, av.w};
      float b[4] = {bv.x, bv.y, bv.z, bv.w};
#pragma unroll
      for (int i = 0; i < 4; ++i)
#pragma unroll
        for (int j = 0; j < 4; ++j) acc[i][j] = fmaf(a[i], b[j], acc[i][j]);
    }
    __syncthreads();
  }
#pragma unroll
  for (int i = 0; i < 4; ++i) {
    int row = row0 + tr * 4 + i;
#pragma unroll
    for (int j = 0; j < 4; ++j) {
      int col = col0 + tc * 4 + j;
      if (col < NC) Ck[(size_t)row * NC + col] = acc[i][j];
    }
  }
}

// W GEMM over 5 pieces (piece0 = state buffer, 1..4 = SG[k]) with fused epilogues.
// mode 0 (gate): zr=sigmoid(acc+b); z -> ubuf[1+col]=z*h; r -> rbuf; ubuf[0]=hbuf[0]
// mode 1 (upd):  hc=tanh(acc+b); h' = r*h + (1-r)*hc -> hbuf[1+col]; col0: hbuf[0]=x_next
__global__ __launch_bounds__(256) void wgemm_kernel(
    const float* Abase, const float* __restrict__ SG, const float* __restrict__ Weff,
    const float* __restrict__ bias, float* hbuf, float* ubuf, float* rbuf,
    const float* __restrict__ xnext, int C, int O, int hid, int mode) {
  __shared__ __align__(16) float sAT[32][68];
  __shared__ __align__(16) float sB[32][68];
  int tid = threadIdx.x;
  int tc = tid & 15, tr = tid >> 4;
  int row0 = blockIdx.y * 64, col0 = blockIdx.x * 64;
  float acc[4][4] = {};
  for (int p = 0; p < 5; ++p) {
    const float* Ap = (p == 0) ? Abase : (SG + (size_t)(p - 1) * ROWS * C);
    for (int cc0 = 0; cc0 < C; cc0 += 32) {
      int kw = C - cc0;
      if (kw > 32) kw = 32;
      for (int i = tid; i < 2048; i += 256) {
        int r = i >> 5, c = i & 31;
        sAT[c][r] = (c < kw) ? Ap[(size_t)(row0 + r) * C + cc0 + c] : 0.0f;
      }
      for (int i = tid; i < 2048; i += 256) {
        int r = i >> 6, c = i & 63;
        int col = col0 + c;
        sB[r][c] = (r < kw && col < O) ? Weff[(size_t)(p * C + cc0 + r) * O + col] : 0.0f;
      }
      __syncthreads();
#pragma unroll
      for (int kk = 0; kk < 32; ++kk) {
        float4 av = *(const float4*)&sAT[kk][tr * 4];
        float4 bv = *(const float4*)&sB[kk][tc * 4];
        float a[4] = {av.x, av.y, av.z, av.w};
        float b[4] = {bv.x, bv.y, bv.z, bv.w};
#pragma unroll
        for (int i = 0; i < 4; ++i)
#pragma unroll
          for (int j = 0; j < 4; ++j) acc[i][j] = fmaf(a[i], b[j], acc[i][j]);
      }
      __syncthreads();
    }
  }
#pragma unroll
  for (int i = 0; i < 4; ++i) {
    int row = row0 + tr * 4 + i;
#pragma unroll
    for (int j = 0; j < 4; ++j) {
      int col = col0 + tc * 4 + j;
      if (col >= O) continue;
      float v = acc[i][j] + bias[col];
      if (mode == 0) {
        float s = 1.0f / (1.0f + expf(-v));
        if (col < hid)
          ubuf[(size_t)row * C + 1 + col] = s * hbuf[(size_t)row * C + 1 + col];
        else
          rbuf[(size_t)row * hid + (col - hid)] = s;
        if (col == 0) ubuf[(size_t)row * C] = hbuf[(size_t)row * C];
      } else {
        float hc = tanhf(v);
        float h = hbuf[(size_t)row * C + 1 + col];
        float r = rbuf[(size_t)row * hid + col];
        float hn = r * h + (1.0f - r) * hc;
        hbuf[(size_t)row * C + 1 + col] = hn;
        if (col == 0 && xnext != nullptr) {
          int b_ = row & 31, n_ = row >> 5;
          hbuf[(size_t)row * C] = xnext[(size_t)b_ * (TLEN * NNODE) + n_];
        }
      }
    }
  }
}

// encoder state init: c0 = x[:,0], h = 0
__global__ void enc_init_kernel(const float* __restrict__ x, float* __restrict__ hbuf) {
  int idx = blockIdx.x * 256 + threadIdx.x;
  if (idx >= ROWS * ENC_C) return;
  int row = idx / ENC_C, c = idx % ENC_C;
  float v = 0.0f;
  if (c == 0) {
    int b = row & 31, n = row >> 5;
    v = x[(size_t)b * (TLEN * NNODE) + n];
  }
  hbuf[idx] = v;
}

// attention + decoder state init: hD = [go=0, h_t, softmax(hWq M^T) M]
__global__ __launch_bounds__(256) void attn_kernel(const float* __restrict__ hE,
                                                   const float* __restrict__ Wq,
                                                   const float* __restrict__ Mem,
                                                   float* __restrict__ hD) {
  int row = blockIdx.x * 256 + threadIdx.x;  // 8192
  const float* h = hE + (size_t)row * ENC_C + 1;
  float q[32];
  for (int j = 0; j < 32; ++j) {
    float s = 0.f;
    for (int c = 0; c < 64; ++c) s = fmaf(h[c], Wq[c * 32 + j], s);
    q[j] = s;
  }
  float l[8], mx = -3.402823466e38f;
  for (int m = 0; m < 8; ++m) {
    float s = 0.f;
    for (int j = 0; j < 32; ++j) s = fmaf(q[j], Mem[m * 32 + j], s);
    l[m] = s;
    mx = fmaxf(mx, s);
  }
  float se = 0.f;
  for (int m = 0; m < 8; ++m) { l[m] = expf(l[m] - mx); se += l[m]; }
  float* d = hD + (size_t)row * DEC_C;
  d[0] = 0.0f;
  for (int c = 0; c < 64; ++c) d[1 + c] = h[c];
  for (int j = 0; j < 32; ++j) {
    float v = 0.f;
    for (int m = 0; m < 8; ++m) v = fmaf(l[m] / se, Mem[m * 32 + j], v);
    d[65 + j] = v;
  }
}

// decoder projection: go = h' @ proj_w + proj_b -> out[b][t][n] and hD[row][0]
__global__ void proj_kernel(float* hD, const float* __restrict__ pw,
                            const float* __restrict__ pb, float* __restrict__ out, int t) {
  int row = blockIdx.x * 256 + threadIdx.x;  // 8192
  const float* h = hD + (size_t)row * DEC_C + 1;
  float s = pb[0];
  for (int c = 0; c < 96; ++c) s = fmaf(h[c], pw[c], s);
  hD[(size_t)row * DEC_C] = s;
  int n = row >> 5, b = row & 31;
  out[(size_t)b * (TLEN * NNODE) + (size_t)t * NNODE + n] = s;
}

// ====================== host launch ======================
extern "C" void kernel_launch(void* const* d_in, const int* in_sizes, int n_in,
                              void* d_out, int out_size, void* d_ws, size_t ws_size,
                              hipStream_t stream) {
  (void)in_sizes; (void)n_in; (void)out_size; (void)ws_size;
  const float* x    = (const float*)d_in[0];
  const float* Mem  = (const float*)d_in[1];
  const float* Wq   = (const float*)d_in[2];
  const float* We1  = (const float*)d_in[3];
  const float* We2  = (const float*)d_in[4];
  const float* egw  = (const float*)d_in[5];
  const float* egb  = (const float*)d_in[6];
  const float* euw  = (const float*)d_in[7];
  const float* eub  = (const float*)d_in[8];
  const float* dgw  = (const float*)d_in[9];
  const float* dgb  = (const float*)d_in[10];
  const float* duw  = (const float*)d_in[11];
  const float* dub  = (const float*)d_in[12];
  const float* pw   = (const float*)d_in[13];
  const float* pb   = (const float*)d_in[14];
  float* out = (float*)d_out;

  // ---- workspace carve (floats, 256B aligned chunks) ----
  float* ws = (float*)d_ws;
  size_t off = 0;
  auto alloc = [&](size_t nf) {
    float* p = ws + off;
    off += (nf + 63) & ~(size_t)63;
    return p;
  };
  float* S    = alloc((size_t)4 * 65536);         // S1_A, T2_A, S1_B, T2_B
  float* e1   = alloc(8192);
  float* e2   = alloc(8192);
  float* n1   = alloc(256);
  float* n2   = alloc(256);
  float* adj  = alloc(65536);
  float* deg  = alloc(256);
  int*   stats = (int*)alloc(64);
  float* WgE  = alloc((size_t)5 * ENC_C * 128);
  float* WuE  = alloc((size_t)5 * ENC_C * 64);
  float* WgD  = alloc((size_t)5 * DEC_C * 192);
  float* WuD  = alloc((size_t)5 * DEC_C * 96);
  float* hE   = alloc((size_t)ROWS * ENC_C);
  float* uE   = alloc((size_t)ROWS * ENC_C);
  float* hD   = alloc((size_t)ROWS * DEC_C);
  float* uD   = alloc((size_t)ROWS * DEC_C);
  float* rE   = alloc((size_t)ROWS * ENC_H);
  float* rD   = alloc((size_t)ROWS * DEC_HID);
  float* SG   = alloc((size_t)4 * ROWS * DEC_C);  // shared enc/dec conv scratch

  // ---- PRNG keys: k1,k2 = jax.random.split(jax.random.key(42)) ----
  uint32_t ka0, ka1, kb0, kb1;
#if PRNG_PARTITIONABLE
  tf2x32(0u, 42u, 0u, 0u, &ka0, &ka1);
  tf2x32(0u, 42u, 0u, 1u, &kb0, &kb1);
#else
  {
    uint32_t a0, a1, b0, b1;
    tf2x32(0u, 42u, 0u, 2u, &a0, &a1);
    tf2x32(0u, 42u, 1u, 3u, &b0, &b1);
    ka0 = a0; ka1 = b0; kb0 = a1; kb1 = b1;
  }
#endif

  // ---- setup ----
  setup_embed_kernel<<<1, 256, 0, stream>>>(We1, We2, Mem, e1, e2, n1, n2);
  stats_init_kernel<<<1, 1, 0, stream>>>(stats);
  adj_kernel<<<256, 256, 0, stream>>>(e1, e2, n1, n2, ka0, ka1, adj, deg, stats);
  lap_kernel<<<256, 256, 0, stream>>>(adj, deg, stats, S);
  t2_kernel<<<dim3(4, 4), 256, 0, stream>>>(S, S + 65536);
  stats_init_kernel<<<1, 1, 0, stream>>>(stats);
  adj_kernel<<<256, 256, 0, stream>>>(e2, e1, n2, n1, kb0, kb1, adj, deg, stats);
  lap_kernel<<<256, 256, 0, stream>>>(adj, deg, stats, S + 2 * 65536);
  t2_kernel<<<dim3(4, 4), 256, 0, stream>>>(S + 2 * 65536, S + 3 * 65536);
  fold_w_kernel<<<(5 * ENC_C * 128 + 255) / 256, 256, 0, stream>>>(egw, WgE, ENC_C, 128);
  fold_w_kernel<<<(5 * ENC_C * 64 + 255) / 256, 256, 0, stream>>>(euw, WuE, ENC_C, 64);
  fold_w_kernel<<<(5 * DEC_C * 192 + 255) / 256, 256, 0, stream>>>(dgw, WgD, DEC_C, 192);
  fold_w_kernel<<<(5 * DEC_C * 96 + 255) / 256, 256, 0, stream>>>(duw, WuD, DEC_C, 96);

  // ---- encoder ----
  const int NC_E = BATCH * ENC_C;  // 2080
  const int CT_E = (NC_E + 63) / 64;  // 33
  enc_init_kernel<<<(ROWS * ENC_C + 255) / 256, 256, 0, stream>>>(x, hE);
  for (int t = 0; t < TLEN; ++t) {
    sconv_kernel<<<dim3(CT_E, 4, 4), 256, 0, stream>>>(S, hE, SG, NC_E);
    wgemm_kernel<<<dim3(2, 128), 256, 0, stream>>>(hE, SG, WgE, egb, hE, uE, rE,
                                                   nullptr, ENC_C, 128, ENC_H, 0);
    sconv_kernel<<<dim3(CT_E, 4, 4), 256, 0, stream>>>(S, uE, SG, NC_E);
    const float* xn = (t + 1 < TLEN) ? (x + (size_t)(t + 1) * NNODE) : nullptr;
    wgemm_kernel<<<dim3(1, 128), 256, 0, stream>>>(uE, SG, WuE, eub, hE, nullptr, rE,
                                                   xn, ENC_C, 64, ENC_H, 1);
  }

  // ---- attention + decoder init ----
  attn_kernel<<<32, 256, 0, stream>>>(hE, Wq, Mem, hD);

  // ---- decoder ----
  const int NC_D = BATCH * DEC_C;  // 3104
  const int CT_D = (NC_D + 63) / 64;  // 49
  for (int t = 0; t < TLEN; ++t) {
    sconv_kernel<<<dim3(CT_D, 4, 4), 256, 0, stream>>>(S, hD, SG, NC_D);
    wgemm_kernel<<<dim3(3, 128), 256, 0, stream>>>(hD, SG, WgD, dgb, hD, uD, rD,
                                                   nullptr, DEC_C, 192, DEC_HID, 0);
    sconv_kernel<<<dim3(CT_D, 4, 4), 256, 0, stream>>>(S, uD, SG, NC_D);
    wgemm_kernel<<<dim3(2, 128), 256, 0, stream>>>(uD, SG, WuD, dub, hD, nullptr, rD,
                                                   nullptr, DEC_C, 96, DEC_HID, 1);
    proj_kernel<<<32, 256, 0, stream>>>(hD, pw, pb, out, t);
  }
}

// Round 2
// 38189.536 us; speedup vs baseline: 1.6791x; 1.6791x over previous
//
#include <hip/hip_runtime.h>
#include <stdint.h>
#include <math.h>

// ====================== problem constants ======================
#define NNODE 256
#define BATCH 32
#define TLEN  128
#define ENC_H 64
#define DEC_HID 96
#define ENC_C 65   // IN_DIM + ENC_H
#define DEC_C 97   // OUT_DIM + DEC_HID
#define ROWS  8192 // NNODE*BATCH
#define CPAD_E 72  // 64 k-slots + ch0 slot(64) + pad -> mult of 8
#define CPAD_D 104 // 96 k-slots + ch0 slot(96) + pad -> mult of 8

typedef unsigned short u16;
typedef short bf16x8 __attribute__((ext_vector_type(8)));
typedef float f32x4 __attribute__((ext_vector_type(4)));

__device__ inline u16 f2bf_rn(float v) {
  uint32_t u = __float_as_uint(v);
  u += 0x7fffu + ((u >> 16) & 1u);
  return (u16)(u >> 16);
}
__device__ inline float bf2f(u16 h) { return __uint_as_float(((uint32_t)h) << 16); }
__device__ inline void split2(float v, u16& hi, u16& lo) {
  hi = f2bf_rn(v);
  lo = f2bf_rn(v - bf2f(hi));
}

// ====================== Threefry-2x32 (20 rounds) ======================
__host__ __device__ inline uint32_t rotl32_(uint32_t v, int d) {
  return (v << d) | (v >> (32 - d));
}
__host__ __device__ inline void tf2x32(uint32_t k0, uint32_t k1, uint32_t x0,
                                       uint32_t x1, uint32_t* o0, uint32_t* o1) {
  uint32_t ks2 = k0 ^ k1 ^ 0x1BD11BDAu;
  x0 += k0; x1 += k1;
  x0 += x1; x1 = rotl32_(x1, 13); x1 ^= x0;
  x0 += x1; x1 = rotl32_(x1, 15); x1 ^= x0;
  x0 += x1; x1 = rotl32_(x1, 26); x1 ^= x0;
  x0 += x1; x1 = rotl32_(x1, 6);  x1 ^= x0;
  x0 += k1; x1 += ks2 + 1u;
  x0 += x1; x1 = rotl32_(x1, 17); x1 ^= x0;
  x0 += x1; x1 = rotl32_(x1, 29); x1 ^= x0;
  x0 += x1; x1 = rotl32_(x1, 16); x1 ^= x0;
  x0 += x1; x1 = rotl32_(x1, 24); x1 ^= x0;
  x0 += ks2; x1 += k0 + 2u;
  x0 += x1; x1 = rotl32_(x1, 13); x1 ^= x0;
  x0 += x1; x1 = rotl32_(x1, 15); x1 ^= x0;
  x0 += x1; x1 = rotl32_(x1, 26); x1 ^= x0;
  x0 += x1; x1 = rotl32_(x1, 6);  x1 ^= x0;
  x0 += k0; x1 += k1 + 3u;
  x0 += x1; x1 = rotl32_(x1, 17); x1 ^= x0;
  x0 += x1; x1 = rotl32_(x1, 29); x1 ^= x0;
  x0 += x1; x1 = rotl32_(x1, 16); x1 ^= x0;
  x0 += x1; x1 = rotl32_(x1, 24); x1 ^= x0;
  x0 += k1; x1 += ks2 + 4u;
  x0 += x1; x1 = rotl32_(x1, 13); x1 ^= x0;
  x0 += x1; x1 = rotl32_(x1, 15); x1 ^= x0;
  x0 += x1; x1 = rotl32_(x1, 26); x1 ^= x0;
  x0 += x1; x1 = rotl32_(x1, 6);  x1 ^= x0;
  x0 += ks2; x1 += k0 + 5u;
  *o0 = x0; *o1 = x1;
}

__device__ inline float gumbel_at(uint32_t k0, uint32_t k1, uint32_t idx) {
  uint32_t o0, o1;
  tf2x32(k0, k1, 0u, idx, &o0, &o1);
  uint32_t b = o0 ^ o1;
  float f = __uint_as_float((b >> 9) | 0x3f800000u) - 1.0f;
  const float tiny = 1.17549435e-38f;
  float u = fmaxf(tiny, f + tiny);
  return -logf(-logf(u));
}

// ====================== graph setup kernels (fp32, one-time) ======================
__global__ __launch_bounds__(256) void setup_embed_kernel(
    const float* __restrict__ We1, const float* __restrict__ We2,
    const float* __restrict__ Mem, float* __restrict__ e1, float* __restrict__ e2,
    float* __restrict__ n1, float* __restrict__ n2) {
  int n = threadIdx.x;
  float a[8];
  float s;
  for (int m = 0; m < 8; ++m) a[m] = We1[n * 8 + m];
  s = 0.f;
  for (int j = 0; j < 32; ++j) {
    float v = 0.f;
    for (int m = 0; m < 8; ++m) v = fmaf(a[m], Mem[m * 32 + j], v);
    e1[n * 32 + j] = v;
    s = fmaf(v, v, s);
  }
  n1[n] = sqrtf(s);
  for (int m = 0; m < 8; ++m) a[m] = We2[n * 8 + m];
  s = 0.f;
  for (int j = 0; j < 32; ++j) {
    float v = 0.f;
    for (int m = 0; m < 8; ++m) v = fmaf(a[m], Mem[m * 32 + j], v);
    e2[n * 32 + j] = v;
    s = fmaf(v, v, s);
  }
  n2[n] = sqrtf(s);
}

__global__ void stats_init_kernel(int* stats) {
  stats[0] = 0;
  stats[1] = 0;
  stats[2] = 0x7fffffff;
}

__global__ __launch_bounds__(256) void adj_kernel(
    const float* __restrict__ eA, const float* __restrict__ eB,
    const float* __restrict__ nA, const float* __restrict__ nB,
    uint32_t k0, uint32_t k1, float* __restrict__ adj, float* __restrict__ deg,
    int* __restrict__ stats) {
  int i = blockIdx.x, j = threadIdx.x;
  float dot = 0.f;
  for (int c = 0; c < 32; ++c) dot = fmaf(eA[i * 32 + c], eB[j * 32 + c], dot);
  float g = dot / (nA[i] * nB[j] + 1e-6f);
  g = (g + 1.0f) * 0.5f;
  uint32_t f = ((uint32_t)(i * 256 + j)) * 2u;
  float g0 = gumbel_at(k0, k1, f);
  float g1 = gumbel_at(k0, k1, f + 1u);
  float a = ((g + g0) >= ((1.0f - g) + g1)) ? 1.0f : 0.0f;
  if (i == j) a = 0.0f;
  adj[i * 256 + j] = a;
  __shared__ float red[256];
  red[j] = a;
  __syncthreads();
  for (int s = 128; s > 0; s >>= 1) {
    if (j < s) red[j] += red[j + s];
    __syncthreads();
  }
  if (j == 0) {
    float d = red[0];
    deg[i] = d;
    atomicMax(&stats[0], (int)d);
    atomicMin(&stats[2], (int)d);
    if (d > 0.5f) atomicOr(&stats[1], 1);
  }
}

__global__ __launch_bounds__(256) void lap_kernel(const float* __restrict__ adj,
                                                  const float* __restrict__ deg,
                                                  const int* __restrict__ stats,
                                                  float* __restrict__ S1) {
  int i = blockIdx.x, j = threadIdx.x;
  float lmax = (float)stats[0];
  float lmin = stats[1] ? -1.0f : (float)stats[2];
  float lam = lmax - lmin;
  float L = (i == j) ? deg[i] : -adj[i * 256 + j];
  S1[i * 256 + j] = 2.0f * L / lam - ((i == j) ? 1.0f : 0.0f);
}

// T2 = 2*(S1@S1) - I  (fp32 VALU tile GEMM, one-time)
__global__ __launch_bounds__(256) void t2_kernel(const float* __restrict__ A,
                                                 float* __restrict__ Cout) {
  __shared__ __align__(16) float sAT[32][68];
  __shared__ __align__(16) float sB[32][68];
  int tid = threadIdx.x;
  int tc = tid & 15, tr = tid >> 4;
  int row0 = blockIdx.y * 64, col0 = blockIdx.x * 64;
  float acc[4][4] = {};
  for (int m0 = 0; m0 < 256; m0 += 32) {
    for (int i = tid; i < 2048; i += 256) {
      int r = i >> 5, c = i & 31;
      sAT[c][r] = A[(size_t)(row0 + r) * 256 + m0 + c];
    }
    for (int i = tid; i < 2048; i += 256) {
      int r = i >> 6, c = i & 63;
      sB[r][c] = A[(size_t)(m0 + r) * 256 + col0 + c];
    }
    __syncthreads();
#pragma unroll
    for (int kk = 0; kk < 32; ++kk) {
      float4 av = *(const float4*)&sAT[kk][tr * 4];
      float4 bv = *(const float4*)&sB[kk][tc * 4];
      float a[4] = {av.x, av.y, av.z, av.w};
      float b[4] = {bv.x, bv.y, bv.z, bv.w};
#pragma unroll
      for (int i = 0; i < 4; ++i)
#pragma unroll
        for (int j = 0; j < 4; ++j) acc[i][j] = fmaf(a[i], b[j], acc[i][j]);
    }
    __syncthreads();
  }
#pragma unroll
  for (int i = 0; i < 4; ++i) {
    int row = row0 + tr * 4 + i;
#pragma unroll
    for (int j = 0; j < 4; ++j) {
      int col = col0 + tc * 4 + j;
      Cout[(size_t)row * 256 + col] = 2.0f * acc[i][j] - ((row == col) ? 1.0f : 0.0f);
    }
  }
}

// S fp32 -> hi/lo bf16
__global__ void cvt_s_kernel(const float* __restrict__ S, u16* __restrict__ Sh,
                             u16* __restrict__ Sl) {
  int idx = blockIdx.x * 256 + threadIdx.x;
  if (idx >= 4 * 65536) return;
  u16 h, l;
  split2(S[idx], h, l);
  Sh[idx] = h; Sl[idx] = l;
}

// Build W fragments: Wf[p][kc][o][kk] = W[(korig*C + 1 + kc*32 + kk)*O + o] (+fold k3->p0)
// w0[p][o] = W[(korig*C + 0)*O + o] (+fold)
__global__ void build_wfrag(const float* __restrict__ W, int C, int O, int hid,
                            u16* __restrict__ WfH, u16* __restrict__ WfL,
                            float* __restrict__ w0) {
  int idx = blockIdx.x * 256 + threadIdx.x;
  int nKC = hid / 32;
  if (idx < 5 * hid * O) {
    int kk = idx & 31;
    int rest = idx >> 5;
    int o = rest % O; rest /= O;
    int kc = rest % nKC;
    int p = rest / nKC;
    int korig = (p == 0) ? 0 : (p + (p >= 3 ? 1 : 0));
    int c = 1 + kc * 32 + kk;
    float v = W[(size_t)(korig * C + c) * O + o];
    if (p == 0) v += W[(size_t)(3 * C + c) * O + o];
    size_t a = (((size_t)(p * nKC + kc) * O) + o) * 32 + kk;
    u16 h, l; split2(v, h, l);
    WfH[a] = h; WfL[a] = l;
  }
  if (idx < 5 * O) {
    int o = idx % O, p = idx / O;
    int korig = (p == 0) ? 0 : (p + (p >= 3 ? 1 : 0));
    float v = W[(size_t)(korig * C + 0) * O + o];
    if (p == 0) v += W[(size_t)(3 * C + 0) * O + o];
    w0[p * O + o] = v;
  }
}

// encoder state init: ch0 = x[:,0], rest 0; writes f32 + hi/lo + transposed hi/lo
__global__ void enc_init2(const float* __restrict__ x, float* __restrict__ hf,
                          u16* __restrict__ hh, u16* __restrict__ hl,
                          u16* __restrict__ hTh, u16* __restrict__ hTl) {
  int idx = blockIdx.x * 256 + threadIdx.x;
  if (idx >= ENC_C * ROWS) return;
  int c = idx / ROWS, col = idx % ROWS;
  int b = col >> 8, n = col & 255;
  float v = (c == 0) ? x[(size_t)b * (TLEN * NNODE) + n] : 0.f;
  hf[idx] = v;
  u16 h, l; split2(v, h, l);
  hh[idx] = h; hl[idx] = l;
  int slot = (c == 0) ? ENC_H : c - 1;
  hTh[(size_t)col * CPAD_E + slot] = h;
  hTl[(size_t)col * CPAD_E + slot] = l;
}

// attention + decoder state init
__global__ __launch_bounds__(128) void attn2(const float* __restrict__ hEf,
                                             const float* __restrict__ Wq,
                                             const float* __restrict__ Mem,
                                             float* __restrict__ hDf,
                                             u16* __restrict__ hDh, u16* __restrict__ hDl,
                                             u16* __restrict__ hDTh, u16* __restrict__ hDTl) {
  int col = blockIdx.x * 128 + threadIdx.x;
  float h[64];
  for (int c = 0; c < 64; ++c) h[c] = hEf[(size_t)(1 + c) * ROWS + col];
  float q[32];
  for (int j = 0; j < 32; ++j) {
    float s = 0.f;
    for (int c = 0; c < 64; ++c) s = fmaf(h[c], Wq[c * 32 + j], s);
    q[j] = s;
  }
  float l[8], mx = -3.402823466e38f;
  for (int m = 0; m < 8; ++m) {
    float s = 0.f;
    for (int j = 0; j < 32; ++j) s = fmaf(q[j], Mem[m * 32 + j], s);
    l[m] = s;
    mx = fmaxf(mx, s);
  }
  float se = 0.f;
  for (int m = 0; m < 8; ++m) { l[m] = expf(l[m] - mx); se += l[m]; }
  float val[32];
  for (int j = 0; j < 32; ++j) {
    float v = 0.f;
    for (int m = 0; m < 8; ++m) v = fmaf(l[m] / se, Mem[m * 32 + j], v);
    val[j] = v;
  }
  for (int c = 0; c < DEC_C; ++c) {
    float v = (c == 0) ? 0.f : ((c <= 64) ? h[c - 1] : val[c - 65]);
    hDf[(size_t)c * ROWS + col] = v;
    u16 hh, ll; split2(v, hh, ll);
    hDh[(size_t)c * ROWS + col] = hh;
    hDl[(size_t)c * ROWS + col] = ll;
    int slot = (c == 0) ? DEC_HID : c - 1;
    hDTh[(size_t)col * CPAD_D + slot] = hh;
    hDTl[(size_t)col * CPAD_D + slot] = ll;
  }
}

// ====================== sconv (MFMA, split bf16) ======================
// OUT[(c,b)][p*256+n] = sum_m A[(c,b)][m] * S_p[n][m]
// A = state straight hi/lo [Mrows][256]; output -> SGT[p][b*256+n][slot(c)] hi/lo
__global__ __launch_bounds__(256) void sconv_mfma(
    const u16* __restrict__ Ahi, const u16* __restrict__ Alo,
    const u16* __restrict__ Shi, const u16* __restrict__ Slo,
    u16* __restrict__ Ghi, u16* __restrict__ Glo,
    int Mrows, int Cpad, int slot0) {
  __shared__ __align__(16) u16 lA0[64 * 40];
  __shared__ __align__(16) u16 lA1[64 * 40];
  __shared__ __align__(16) u16 lB0[128 * 40];
  __shared__ __align__(16) u16 lB1[128 * 40];
  int tid = threadIdx.x;
  int wid = tid >> 6, lane = tid & 63;
  int wm = wid >> 1, wn = wid & 1;
  int by = blockIdx.y, bx = blockIdx.x;
  int p = bx >> 1;
  int nbase = (bx & 1) * 128;
  const u16* Sh = Shi + (size_t)p * 65536;
  const u16* Sl = Slo + (size_t)p * 65536;
  int g = lane >> 4, li = lane & 15;
  f32x4 acc[2][4];
#pragma unroll
  for (int i = 0; i < 2; ++i)
#pragma unroll
    for (int j = 0; j < 4; ++j) acc[i][j] = (f32x4){0.f, 0.f, 0.f, 0.f};

  for (int m0 = 0; m0 < 256; m0 += 32) {
    {
      int r = tid >> 2, seg = tid & 3;
      int grow = by * 64 + r;
      uint4 vh = make_uint4(0, 0, 0, 0), vl = make_uint4(0, 0, 0, 0);
      if (grow < Mrows) {
        vh = *(const uint4*)(Ahi + (size_t)grow * 256 + m0 + seg * 8);
        vl = *(const uint4*)(Alo + (size_t)grow * 256 + m0 + seg * 8);
      }
      *(uint4*)&lA0[r * 40 + seg * 8] = vh;
      *(uint4*)&lA1[r * 40 + seg * 8] = vl;
    }
    for (int it = tid; it < 512; it += 256) {
      int r = it >> 2, seg = it & 3;
      int n = nbase + r;
      *(uint4*)&lB0[r * 40 + seg * 8] = *(const uint4*)(Sh + (size_t)n * 256 + m0 + seg * 8);
      *(uint4*)&lB1[r * 40 + seg * 8] = *(const uint4*)(Sl + (size_t)n * 256 + m0 + seg * 8);
    }
    __syncthreads();
    bf16x8 a_h[2], a_l[2], b_h[4], b_l[4];
#pragma unroll
    for (int mf = 0; mf < 2; ++mf) {
      int row = wm * 32 + 16 * mf + li;
      a_h[mf] = *(const bf16x8*)&lA0[row * 40 + g * 8];
      a_l[mf] = *(const bf16x8*)&lA1[row * 40 + g * 8];
    }
#pragma unroll
    for (int nf = 0; nf < 4; ++nf) {
      int nl = wn * 64 + 16 * nf + li;
      b_h[nf] = *(const bf16x8*)&lB0[nl * 40 + g * 8];
      b_l[nf] = *(const bf16x8*)&lB1[nl * 40 + g * 8];
    }
#pragma unroll
    for (int mf = 0; mf < 2; ++mf)
#pragma unroll
      for (int nf = 0; nf < 4; ++nf) {
        acc[mf][nf] = __builtin_amdgcn_mfma_f32_16x16x32_bf16(a_h[mf], b_h[nf], acc[mf][nf], 0, 0, 0);
        acc[mf][nf] = __builtin_amdgcn_mfma_f32_16x16x32_bf16(a_h[mf], b_l[nf], acc[mf][nf], 0, 0, 0);
        acc[mf][nf] = __builtin_amdgcn_mfma_f32_16x16x32_bf16(a_l[mf], b_h[nf], acc[mf][nf], 0, 0, 0);
      }
    __syncthreads();
  }
  u16* Gh = Ghi + (size_t)p * ROWS * Cpad;
  u16* Gl = Glo + (size_t)p * ROWS * Cpad;
#pragma unroll
  for (int mf = 0; mf < 2; ++mf) {
    int rowq = by * 64 + wm * 32 + 16 * mf + 4 * g;
#pragma unroll
    for (int nf = 0; nf < 4; ++nf) {
      int n = nbase + wn * 64 + 16 * nf + li;
#pragma unroll
      for (int r = 0; r < 4; ++r) {
        int row = rowq + r;
        if (row < Mrows) {
          int c = row >> 5, b = row & 31;
          int slot = (c == 0) ? slot0 : c - 1;
          size_t addr = ((size_t)b * 256 + n) * Cpad + slot;
          u16 h_, l_;
          split2(acc[mf][nf][r], h_, l_);
          Gh[addr] = h_;
          Gl[addr] = l_;
        }
      }
    }
  }
}

// ====================== wgemm (MFMA, split bf16, fused epilogues) ======================
// OUT[o][col] = bias[o] + sum_p { w0[p][o]*in0_p[col] + sum_k Wf_p[o][k]*B_p[col][k] }
// MODE 0: gate (sigmoid; z*h -> ubuf straight+T; r -> rbuf)
// MODE 1: upd-enc (tanh; h' = r*h+(1-r)*hc -> state f32+straight+T; ch0 <- x[t+1])
// MODE 2: upd-dec (same + fused proj -> go -> ch0 + out[b][t][n])
template <int BM, int MODE>
__global__ __launch_bounds__(BM * 4) void wgemm_mfma(
    const u16* __restrict__ WfH, const u16* __restrict__ WfL,
    const float* __restrict__ w0,
    const u16* __restrict__ B0h, const u16* __restrict__ B0l,
    const u16* __restrict__ SGh, const u16* __restrict__ SGl,
    const float* __restrict__ bias,
    float* __restrict__ stF,
    int O, int hid, int Cpad, int slot0,
    u16* __restrict__ uH, u16* __restrict__ uL,
    u16* __restrict__ uTH, u16* __restrict__ uTL,
    float* __restrict__ rbuf,
    u16* __restrict__ stH, u16* __restrict__ stL,
    u16* __restrict__ stTH, u16* __restrict__ stTL,
    const float* __restrict__ xsrc, int tnext,
    const float* __restrict__ pw, const float* __restrict__ pb,
    float* __restrict__ outp, int tcur) {
  constexpr int SMEM_STAGE = 2 * BM * 40 * 2 + 2 * 128 * 40 * 2;
  constexpr int SMEM = (MODE == 2 && SMEM_STAGE < 96 * 128 * 4) ? 96 * 128 * 4 : SMEM_STAGE;
  __shared__ __align__(16) char smem[SMEM];
  u16* lA0 = (u16*)smem;
  u16* lA1 = lA0 + BM * 40;
  u16* lB0 = lA1 + BM * 40;
  u16* lB1 = lB0 + 128 * 40;
  float* projL = (float*)smem;

  int tid = threadIdx.x;
  int wid = tid >> 6, lane = tid & 63;
  int wm = wid >> 1, wn = wid & 1;
  int bx = blockIdx.x;
  int o0 = blockIdx.y * BM;
  int nKC = hid / 32;
  int g = lane >> 4, li = lane & 15;

  f32x4 acc[2][4];
#pragma unroll
  for (int i = 0; i < 2; ++i)
#pragma unroll
    for (int j = 0; j < 4; ++j) acc[i][j] = (f32x4){0.f, 0.f, 0.f, 0.f};

  for (int p = 0; p < 5; ++p) {
    const u16* Bh = (p == 0) ? B0h : SGh + (size_t)(p - 1) * ROWS * Cpad;
    const u16* Bl = (p == 0) ? B0l : SGl + (size_t)(p - 1) * ROWS * Cpad;
    for (int kc = 0; kc < nKC; ++kc) {
      {
        int r = tid >> 2, seg = tid & 3;
        size_t wbase = (((size_t)(p * nKC + kc)) * O + (o0 + r)) * 32 + seg * 8;
        *(uint4*)&lA0[r * 40 + seg * 8] = *(const uint4*)(WfH + wbase);
        *(uint4*)&lA1[r * 40 + seg * 8] = *(const uint4*)(WfL + wbase);
      }
      for (int it = tid; it < 512; it += BM * 4) {
        int cl = it >> 2, seg = it & 3;
        size_t a = (size_t)(bx * 128 + cl) * Cpad + kc * 32 + seg * 8;
        *(uint4*)&lB0[cl * 40 + seg * 8] = *(const uint4*)(Bh + a);
        *(uint4*)&lB1[cl * 40 + seg * 8] = *(const uint4*)(Bl + a);
      }
      __syncthreads();
      bf16x8 a_h[2], a_l[2], b_h[4], b_l[4];
#pragma unroll
      for (int mf = 0; mf < 2; ++mf) {
        int row = wm * 32 + 16 * mf + li;
        a_h[mf] = *(const bf16x8*)&lA0[row * 40 + g * 8];
        a_l[mf] = *(const bf16x8*)&lA1[row * 40 + g * 8];
      }
#pragma unroll
      for (int nf = 0; nf < 4; ++nf) {
        int nl = wn * 64 + 16 * nf + li;
        b_h[nf] = *(const bf16x8*)&lB0[nl * 40 + g * 8];
        b_l[nf] = *(const bf16x8*)&lB1[nl * 40 + g * 8];
      }
#pragma unroll
      for (int mf = 0; mf < 2; ++mf)
#pragma unroll
        for (int nf = 0; nf < 4; ++nf) {
          acc[mf][nf] = __builtin_amdgcn_mfma_f32_16x16x32_bf16(a_h[mf], b_h[nf], acc[mf][nf], 0, 0, 0);
          acc[mf][nf] = __builtin_amdgcn_mfma_f32_16x16x32_bf16(a_h[mf], b_l[nf], acc[mf][nf], 0, 0, 0);
          acc[mf][nf] = __builtin_amdgcn_mfma_f32_16x16x32_bf16(a_l[mf], b_h[nf], acc[mf][nf], 0, 0, 0);
        }
      __syncthreads();
    }
  }

  // ---- epilogue ----
  float in0[5][4];
#pragma unroll
  for (int nf = 0; nf < 4; ++nf) {
    int col = bx * 128 + wn * 64 + 16 * nf + li;
    in0[0][nf] = stF[col];
    for (int p = 1; p < 5; ++p) {
      size_t a = (size_t)(p - 1) * ROWS * Cpad + (size_t)col * Cpad + slot0;
      in0[p][nf] = bf2f(SGh[a]) + bf2f(SGl[a]);
    }
  }
  __syncthreads();  // all ch0/smem reads done before ch0 writes / smem reuse

#pragma unroll
  for (int mf = 0; mf < 2; ++mf) {
    int oq = o0 + wm * 32 + 16 * mf + 4 * g;
#pragma unroll
    for (int nf = 0; nf < 4; ++nf) {
      int col = bx * 128 + wn * 64 + 16 * nf + li;
      u16 qh[4], ql[4];
      bool quad_store = false;
#pragma unroll
      for (int r = 0; r < 4; ++r) {
        int o = oq + r;
        float v = acc[mf][nf][r] + bias[o];
#pragma unroll
        for (int p = 0; p < 5; ++p) v = fmaf(w0[p * O + o], in0[p][nf], v);
        if (MODE == 0) {
          float s = 1.0f / (1.0f + expf(-v));
          if (o < hid) {
            float u = s * stF[(size_t)(1 + o) * ROWS + col];
            u16 h_, l_;
            split2(u, h_, l_);
            uH[(size_t)(1 + o) * ROWS + col] = h_;
            uL[(size_t)(1 + o) * ROWS + col] = l_;
            qh[r] = h_; ql[r] = l_;
            quad_store = true;
          } else {
            rbuf[(size_t)(o - hid) * ROWS + col] = s;
          }
        } else {
          float hc = tanhf(v);
          float hprev = stF[(size_t)(1 + o) * ROWS + col];
          float rr = rbuf[(size_t)o * ROWS + col];
          float hn = rr * hprev + (1.0f - rr) * hc;
          stF[(size_t)(1 + o) * ROWS + col] = hn;
          u16 h_, l_;
          split2(hn, h_, l_);
          stH[(size_t)(1 + o) * ROWS + col] = h_;
          stL[(size_t)(1 + o) * ROWS + col] = l_;
          qh[r] = h_; ql[r] = l_;
          quad_store = true;
          if (MODE == 2) projL[o * 128 + (col - bx * 128)] = hn;
        }
      }
      if (quad_store) {
        u16* TH = (MODE == 0) ? uTH : stTH;
        u16* TL = (MODE == 0) ? uTL : stTL;
        uint2 vh, vl;
        vh.x = (uint32_t)qh[0] | ((uint32_t)qh[1] << 16);
        vh.y = (uint32_t)qh[2] | ((uint32_t)qh[3] << 16);
        vl.x = (uint32_t)ql[0] | ((uint32_t)ql[1] << 16);
        vl.y = (uint32_t)ql[2] | ((uint32_t)ql[3] << 16);
        *(uint2*)&TH[(size_t)col * Cpad + oq] = vh;
        *(uint2*)&TL[(size_t)col * Cpad + oq] = vl;
      }
    }
  }

  if (MODE == 0) {
    // ch0 copy into ubuf (only block owning o==0)
    if (o0 == 0 && tid < 128) {
      int col = bx * 128 + tid;
      float x0 = stF[col];
      u16 h_, l_;
      split2(x0, h_, l_);
      uH[col] = h_; uL[col] = l_;
      uTH[(size_t)col * Cpad + slot0] = h_;
      uTL[(size_t)col * Cpad + slot0] = l_;
    }
  }
  if (MODE == 1) {
    __syncthreads();
    if (tid < 128) {
      int col = bx * 128 + tid;
      int b = col >> 8, n = col & 255;
      float xv = (tnext >= 0) ? xsrc[(size_t)b * (TLEN * NNODE) + (size_t)tnext * 256 + n]
                              : stF[col];
      stF[col] = xv;
      u16 h_, l_;
      split2(xv, h_, l_);
      stH[col] = h_; stL[col] = l_;
      stTH[(size_t)col * Cpad + slot0] = h_;
      stTL[(size_t)col * Cpad + slot0] = l_;
    }
  }
  if (MODE == 2) {
    __syncthreads();  // projL complete
    if (tid < 128) {
      int col = bx * 128 + tid;
      float s = pb[0];
      for (int o = 0; o < 96; ++o) s = fmaf(pw[o], projL[o * 128 + tid], s);
      stF[col] = s;
      u16 h_, l_;
      split2(s, h_, l_);
      stH[col] = h_; stL[col] = l_;
      stTH[(size_t)col * Cpad + slot0] = h_;
      stTL[(size_t)col * Cpad + slot0] = l_;
      int b = col >> 8, n = col & 255;
      outp[(size_t)b * (TLEN * NNODE) + (size_t)tcur * 256 + n] = s;
    }
  }
}

// ====================== host launch ======================
extern "C" void kernel_launch(void* const* d_in, const int* in_sizes, int n_in,
                              void* d_out, int out_size, void* d_ws, size_t ws_size,
                              hipStream_t stream) {
  (void)in_sizes; (void)n_in; (void)out_size; (void)ws_size;
  const float* x   = (const float*)d_in[0];
  const float* Mem = (const float*)d_in[1];
  const float* Wq  = (const float*)d_in[2];
  const float* We1 = (const float*)d_in[3];
  const float* We2 = (const float*)d_in[4];
  const float* egw = (const float*)d_in[5];
  const float* egb = (const float*)d_in[6];
  const float* euw = (const float*)d_in[7];
  const float* eub = (const float*)d_in[8];
  const float* dgw = (const float*)d_in[9];
  const float* dgb = (const float*)d_in[10];
  const float* duw = (const float*)d_in[11];
  const float* dub = (const float*)d_in[12];
  const float* pw  = (const float*)d_in[13];
  const float* pb  = (const float*)d_in[14];
  float* out = (float*)d_out;

  float* ws = (float*)d_ws;
  size_t off = 0;
  auto allocf = [&](size_t nf) {
    float* p = ws + off;
    off += (nf + 63) & ~(size_t)63;
    return p;
  };
  auto allocu = [&](size_t nu) { return (u16*)allocf((nu + 1) / 2); };

  float* Sf  = allocf(4 * 65536);
  float* e1  = allocf(8192);
  float* e2  = allocf(8192);
  float* n1  = allocf(256);
  float* n2  = allocf(256);
  float* adj = allocf(65536);
  float* deg = allocf(256);
  int* stats = (int*)allocf(64);
  float* rb  = allocf((size_t)96 * ROWS);
  float* hEf = allocf((size_t)ENC_C * ROWS);
  float* hDf = allocf((size_t)DEC_C * ROWS);
  float* w0gE = allocf(5 * 128);
  float* w0uE = allocf(5 * 64);
  float* w0gD = allocf(5 * 192);
  float* w0uD = allocf(5 * 96);

  u16* Sh = allocu(4 * 65536);
  u16* Sl = allocu(4 * 65536);
  u16* hEh = allocu((size_t)ENC_C * ROWS);
  u16* hEl = allocu((size_t)ENC_C * ROWS);
  u16* hETh = allocu((size_t)ROWS * CPAD_E);
  u16* hETl = allocu((size_t)ROWS * CPAD_E);
  u16* uEh = allocu((size_t)ENC_C * ROWS);
  u16* uEl = allocu((size_t)ENC_C * ROWS);
  u16* uETh = allocu((size_t)ROWS * CPAD_E);
  u16* uETl = allocu((size_t)ROWS * CPAD_E);
  u16* hDh = allocu((size_t)DEC_C * ROWS);
  u16* hDl = allocu((size_t)DEC_C * ROWS);
  u16* hDTh = allocu((size_t)ROWS * CPAD_D);
  u16* hDTl = allocu((size_t)ROWS * CPAD_D);
  u16* uDh = allocu((size_t)DEC_C * ROWS);
  u16* uDl = allocu((size_t)DEC_C * ROWS);
  u16* uDTh = allocu((size_t)ROWS * CPAD_D);
  u16* uDTl = allocu((size_t)ROWS * CPAD_D);
  u16* SGTh = allocu((size_t)4 * ROWS * CPAD_D);
  u16* SGTl = allocu((size_t)4 * ROWS * CPAD_D);
  u16* WgEh = allocu((size_t)5 * 2 * 128 * 32);
  u16* WgEl = allocu((size_t)5 * 2 * 128 * 32);
  u16* WuEh = allocu((size_t)5 * 2 * 64 * 32);
  u16* WuEl = allocu((size_t)5 * 2 * 64 * 32);
  u16* WgDh = allocu((size_t)5 * 3 * 192 * 32);
  u16* WgDl = allocu((size_t)5 * 3 * 192 * 32);
  u16* WuDh = allocu((size_t)5 * 3 * 96 * 32);
  u16* WuDl = allocu((size_t)5 * 3 * 96 * 32);

  // ---- PRNG keys (jax partitionable threefry) ----
  uint32_t ka0, ka1, kb0, kb1;
  tf2x32(0u, 42u, 0u, 0u, &ka0, &ka1);
  tf2x32(0u, 42u, 0u, 1u, &kb0, &kb1);

  // ---- graph setup ----
  setup_embed_kernel<<<1, 256, 0, stream>>>(We1, We2, Mem, e1, e2, n1, n2);
  stats_init_kernel<<<1, 1, 0, stream>>>(stats);
  adj_kernel<<<256, 256, 0, stream>>>(e1, e2, n1, n2, ka0, ka1, adj, deg, stats);
  lap_kernel<<<256, 256, 0, stream>>>(adj, deg, stats, Sf);
  t2_kernel<<<dim3(4, 4), 256, 0, stream>>>(Sf, Sf + 65536);
  stats_init_kernel<<<1, 1, 0, stream>>>(stats);
  adj_kernel<<<256, 256, 0, stream>>>(e2, e1, n2, n1, kb0, kb1, adj, deg, stats);
  lap_kernel<<<256, 256, 0, stream>>>(adj, deg, stats, Sf + 2 * 65536);
  t2_kernel<<<dim3(4, 4), 256, 0, stream>>>(Sf + 2 * 65536, Sf + 3 * 65536);
  cvt_s_kernel<<<1024, 256, 0, stream>>>(Sf, Sh, Sl);
  build_wfrag<<<(5 * 64 * 128 + 255) / 256, 256, 0, stream>>>(egw, ENC_C, 128, 64, WgEh, WgEl, w0gE);
  build_wfrag<<<(5 * 64 * 64 + 255) / 256, 256, 0, stream>>>(euw, ENC_C, 64, 64, WuEh, WuEl, w0uE);
  build_wfrag<<<(5 * 96 * 192 + 255) / 256, 256, 0, stream>>>(dgw, DEC_C, 192, 96, WgDh, WgDl, w0gD);
  build_wfrag<<<(5 * 96 * 96 + 255) / 256, 256, 0, stream>>>(duw, DEC_C, 96, 96, WuDh, WuDl, w0uD);

  // ---- encoder ----
  enc_init2<<<(ENC_C * ROWS + 255) / 256, 256, 0, stream>>>(x, hEf, hEh, hEl, hETh, hETl);
  for (int t = 0; t < TLEN; ++t) {
    sconv_mfma<<<dim3(8, 33), 256, 0, stream>>>(hEh, hEl, Sh, Sl, SGTh, SGTl, ENC_C * 32, CPAD_E, ENC_H);
    wgemm_mfma<64, 0><<<dim3(64, 2), 256, 0, stream>>>(
        WgEh, WgEl, w0gE, hETh, hETl, SGTh, SGTl, egb, hEf, 128, ENC_H, CPAD_E, ENC_H,
        uEh, uEl, uETh, uETl, rb, nullptr, nullptr, nullptr, nullptr, nullptr, -1,
        nullptr, nullptr, nullptr, 0);
    sconv_mfma<<<dim3(8, 33), 256, 0, stream>>>(uEh, uEl, Sh, Sl, SGTh, SGTl, ENC_C * 32, CPAD_E, ENC_H);
    wgemm_mfma<64, 1><<<dim3(64, 1), 256, 0, stream>>>(
        WuEh, WuEl, w0uE, uETh, uETl, SGTh, SGTl, eub, hEf, 64, ENC_H, CPAD_E, ENC_H,
        nullptr, nullptr, nullptr, nullptr, rb, hEh, hEl, hETh, hETl,
        x, (t + 1 < TLEN) ? (t + 1) : -1, nullptr, nullptr, nullptr, 0);
  }

  // ---- attention + decoder init ----
  attn2<<<64, 128, 0, stream>>>(hEf, Wq, Mem, hDf, hDh, hDl, hDTh, hDTl);

  // ---- decoder ----
  for (int t = 0; t < TLEN; ++t) {
    sconv_mfma<<<dim3(8, 49), 256, 0, stream>>>(hDh, hDl, Sh, Sl, SGTh, SGTl, DEC_C * 32, CPAD_D, DEC_HID);
    wgemm_mfma<64, 0><<<dim3(64, 3), 256, 0, stream>>>(
        WgDh, WgDl, w0gD, hDTh, hDTl, SGTh, SGTl, dgb, hDf, 192, DEC_HID, CPAD_D, DEC_HID,
        uDh, uDl, uDTh, uDTl, rb, nullptr, nullptr, nullptr, nullptr, nullptr, -1,
        nullptr, nullptr, nullptr, 0);
    sconv_mfma<<<dim3(8, 49), 256, 0, stream>>>(uDh, uDl, Sh, Sl, SGTh, SGTl, DEC_C * 32, CPAD_D, DEC_HID);
    wgemm_mfma<96, 2><<<dim3(64, 1), 384, 0, stream>>>(
        WuDh, WuDl, w0uD, uDTh, uDTl, SGTh, SGTl, dub, hDf, 96, DEC_HID, CPAD_D, DEC_HID,
        nullptr, nullptr, nullptr, nullptr, rb, hDh, hDl, hDTh, hDTl,
        nullptr, -1, pw, pb, out, t);
  }
}

// Round 3
// 19716.866 us; speedup vs baseline: 3.2522x; 1.9369x over previous
//
#include <hip/hip_runtime.h>
#include <stdint.h>
#include <math.h>

// ====================== problem constants ======================
#define NNODE 256
#define BATCH 32
#define TLEN  128
#define ROWS  8192 // NNODE*BATCH

typedef unsigned short u16;
typedef short bf16x8 __attribute__((ext_vector_type(8)));
typedef float f32x4 __attribute__((ext_vector_type(4)));

__device__ inline u16 f2bf_rn(float v) {
  uint32_t u = __float_as_uint(v);
  u += 0x7fffu + ((u >> 16) & 1u);
  return (u16)(u >> 16);
}
__device__ inline float bf2f(u16 h) { return __uint_as_float(((uint32_t)h) << 16); }
__device__ inline void split2(float v, u16& hi, u16& lo) {
  hi = f2bf_rn(v);
  lo = f2bf_rn(v - bf2f(hi));
}

// ====================== Threefry-2x32 (20 rounds) ======================
__host__ __device__ inline uint32_t rotl32_(uint32_t v, int d) {
  return (v << d) | (v >> (32 - d));
}
__host__ __device__ inline void tf2x32(uint32_t k0, uint32_t k1, uint32_t x0,
                                       uint32_t x1, uint32_t* o0, uint32_t* o1) {
  uint32_t ks2 = k0 ^ k1 ^ 0x1BD11BDAu;
  x0 += k0; x1 += k1;
  x0 += x1; x1 = rotl32_(x1, 13); x1 ^= x0;
  x0 += x1; x1 = rotl32_(x1, 15); x1 ^= x0;
  x0 += x1; x1 = rotl32_(x1, 26); x1 ^= x0;
  x0 += x1; x1 = rotl32_(x1, 6);  x1 ^= x0;
  x0 += k1; x1 += ks2 + 1u;
  x0 += x1; x1 = rotl32_(x1, 17); x1 ^= x0;
  x0 += x1; x1 = rotl32_(x1, 29); x1 ^= x0;
  x0 += x1; x1 = rotl32_(x1, 16); x1 ^= x0;
  x0 += x1; x1 = rotl32_(x1, 24); x1 ^= x0;
  x0 += ks2; x1 += k0 + 2u;
  x0 += x1; x1 = rotl32_(x1, 13); x1 ^= x0;
  x0 += x1; x1 = rotl32_(x1, 15); x1 ^= x0;
  x0 += x1; x1 = rotl32_(x1, 26); x1 ^= x0;
  x0 += x1; x1 = rotl32_(x1, 6);  x1 ^= x0;
  x0 += k0; x1 += k1 + 3u;
  x0 += x1; x1 = rotl32_(x1, 17); x1 ^= x0;
  x0 += x1; x1 = rotl32_(x1, 29); x1 ^= x0;
  x0 += x1; x1 = rotl32_(x1, 16); x1 ^= x0;
  x0 += x1; x1 = rotl32_(x1, 24); x1 ^= x0;
  x0 += k1; x1 += ks2 + 4u;
  x0 += x1; x1 = rotl32_(x1, 13); x1 ^= x0;
  x0 += x1; x1 = rotl32_(x1, 15); x1 ^= x0;
  x0 += x1; x1 = rotl32_(x1, 26); x1 ^= x0;
  x0 += x1; x1 = rotl32_(x1, 6);  x1 ^= x0;
  x0 += ks2; x1 += k0 + 5u;
  *o0 = x0; *o1 = x1;
}

__device__ inline float gumbel_at(uint32_t k0, uint32_t k1, uint32_t idx) {
  uint32_t o0, o1;
  tf2x32(k0, k1, 0u, idx, &o0, &o1);
  uint32_t b = o0 ^ o1;
  float f = __uint_as_float((b >> 9) | 0x3f800000u) - 1.0f;
  const float tiny = 1.17549435e-38f;
  float u = fmaxf(tiny, f + tiny);
  return -logf(-logf(u));
}

// ====================== graph setup kernels (fp32, one-time) ======================
__global__ __launch_bounds__(256) void setup_embed_kernel(
    const float* __restrict__ We1, const float* __restrict__ We2,
    const float* __restrict__ Mem, float* __restrict__ e1, float* __restrict__ e2,
    float* __restrict__ n1, float* __restrict__ n2) {
  int n = threadIdx.x;
  float a[8];
  float s;
  for (int m = 0; m < 8; ++m) a[m] = We1[n * 8 + m];
  s = 0.f;
  for (int j = 0; j < 32; ++j) {
    float v = 0.f;
    for (int m = 0; m < 8; ++m) v = fmaf(a[m], Mem[m * 32 + j], v);
    e1[n * 32 + j] = v;
    s = fmaf(v, v, s);
  }
  n1[n] = sqrtf(s);
  for (int m = 0; m < 8; ++m) a[m] = We2[n * 8 + m];
  s = 0.f;
  for (int j = 0; j < 32; ++j) {
    float v = 0.f;
    for (int m = 0; m < 8; ++m) v = fmaf(a[m], Mem[m * 32 + j], v);
    e2[n * 32 + j] = v;
    s = fmaf(v, v, s);
  }
  n2[n] = sqrtf(s);
}

__global__ void stats_init_kernel(int* stats) {
  stats[0] = 0;
  stats[1] = 0;
  stats[2] = 0x7fffffff;
}

__global__ __launch_bounds__(256) void adj_kernel(
    const float* __restrict__ eA, const float* __restrict__ eB,
    const float* __restrict__ nA, const float* __restrict__ nB,
    uint32_t k0, uint32_t k1, float* __restrict__ adj, float* __restrict__ deg,
    int* __restrict__ stats) {
  int i = blockIdx.x, j = threadIdx.x;
  float dot = 0.f;
  for (int c = 0; c < 32; ++c) dot = fmaf(eA[i * 32 + c], eB[j * 32 + c], dot);
  float g = dot / (nA[i] * nB[j] + 1e-6f);
  g = (g + 1.0f) * 0.5f;
  uint32_t f = ((uint32_t)(i * 256 + j)) * 2u;
  float g0 = gumbel_at(k0, k1, f);
  float g1 = gumbel_at(k0, k1, f + 1u);
  float a = ((g + g0) >= ((1.0f - g) + g1)) ? 1.0f : 0.0f;
  if (i == j) a = 0.0f;
  adj[i * 256 + j] = a;
  __shared__ float red[256];
  red[j] = a;
  __syncthreads();
  for (int s = 128; s > 0; s >>= 1) {
    if (j < s) red[j] += red[j + s];
    __syncthreads();
  }
  if (j == 0) {
    float d = red[0];
    deg[i] = d;
    atomicMax(&stats[0], (int)d);
    atomicMin(&stats[2], (int)d);
    if (d > 0.5f) atomicOr(&stats[1], 1);
  }
}

__global__ __launch_bounds__(256) void lap_kernel(const float* __restrict__ adj,
                                                  const float* __restrict__ deg,
                                                  const int* __restrict__ stats,
                                                  float* __restrict__ S1) {
  int i = blockIdx.x, j = threadIdx.x;
  float lmax = (float)stats[0];
  float lmin = stats[1] ? -1.0f : (float)stats[2];
  float lam = lmax - lmin;
  float L = (i == j) ? deg[i] : -adj[i * 256 + j];
  S1[i * 256 + j] = 2.0f * L / lam - ((i == j) ? 1.0f : 0.0f);
}

// T2 = 2*(S1@S1) - I  (fp32 VALU tile GEMM, one-time)
__global__ __launch_bounds__(256) void t2_kernel(const float* __restrict__ A,
                                                 float* __restrict__ Cout) {
  __shared__ __align__(16) float sAT[32][68];
  __shared__ __align__(16) float sB[32][68];
  int tid = threadIdx.x;
  int tc = tid & 15, tr = tid >> 4;
  int row0 = blockIdx.y * 64, col0 = blockIdx.x * 64;
  float acc[4][4] = {};
  for (int m0 = 0; m0 < 256; m0 += 32) {
    for (int i = tid; i < 2048; i += 256) {
      int r = i >> 5, c = i & 31;
      sAT[c][r] = A[(size_t)(row0 + r) * 256 + m0 + c];
    }
    for (int i = tid; i < 2048; i += 256) {
      int r = i >> 6, c = i & 63;
      sB[r][c] = A[(size_t)(m0 + r) * 256 + col0 + c];
    }
    __syncthreads();
#pragma unroll
    for (int kk = 0; kk < 32; ++kk) {
      float4 av = *(const float4*)&sAT[kk][tr * 4];
      float4 bv = *(const float4*)&sB[kk][tc * 4];
      float a[4] = {av.x, av.y, av.z, av.w};
      float b[4] = {bv.x, bv.y, bv.z, bv.w};
#pragma unroll
      for (int i = 0; i < 4; ++i)
#pragma unroll
        for (int j = 0; j < 4; ++j) acc[i][j] = fmaf(a[i], b[j], acc[i][j]);
    }
    __syncthreads();
  }
#pragma unroll
  for (int i = 0; i < 4; ++i) {
    int row = row0 + tr * 4 + i;
#pragma unroll
    for (int j = 0; j < 4; ++j) {
      int col = col0 + tc * 4 + j;
      Cout[(size_t)row * 256 + col] = 2.0f * acc[i][j] - ((row == col) ? 1.0f : 0.0f);
    }
  }
}

// S fp32 -> hi/lo bf16
__global__ void cvt_s_kernel(const float* __restrict__ S, u16* __restrict__ Sh,
                             u16* __restrict__ Sl) {
  int idx = blockIdx.x * 256 + threadIdx.x;
  if (idx >= 4 * 65536) return;
  u16 h, l;
  split2(S[idx], h, l);
  Sh[idx] = h; Sl[idx] = l;
}

// W fragments with slot=c mapping: Wf[(p*nKC+kc)*O + o][kk] = W[(korig*C + c)*O+o],
// c = kc*32+kk; c==0 -> 0 (ch0 via rank-1 w0); c==hid excluded (rank-1 wlast).
__global__ void build_wfrag(const float* __restrict__ W, int C, int O, int hid,
                            u16* __restrict__ WfH, u16* __restrict__ WfL,
                            float* __restrict__ w0, float* __restrict__ wlast) {
  int idx = blockIdx.x * 256 + threadIdx.x;
  int nKC = hid / 32;
  if (idx < 5 * hid * O) {
    int kk = idx & 31;
    int rest = idx >> 5;
    int o = rest % O; rest /= O;
    int kc = rest % nKC;
    int p = rest / nKC;
    int korig = (p == 0) ? 0 : (p + (p >= 3 ? 1 : 0));
    int c = kc * 32 + kk;
    float v = 0.f;
    if (c > 0) {
      v = W[(size_t)(korig * C + c) * O + o];
      if (p == 0) v += W[(size_t)(3 * C + c) * O + o];
    }
    size_t a = (((size_t)(p * nKC + kc)) * O + o) * 32 + kk;
    u16 h, l; split2(v, h, l);
    WfH[a] = h; WfL[a] = l;
  }
  if (idx < 5 * O) {
    int o = idx % O, p = idx / O;
    int korig = (p == 0) ? 0 : (p + (p >= 3 ? 1 : 0));
    float v0 = W[(size_t)(korig * C + 0) * O + o];
    if (p == 0) v0 += W[(size_t)(3 * C + 0) * O + o];
    w0[p * O + o] = v0;
    float vl = W[(size_t)(korig * C + hid) * O + o];
    if (p == 0) vl += W[(size_t)(3 * C + hid) * O + o];
    wlast[p * O + o] = vl;
  }
}

// encoder state init: ch0 = x[:,0], rest 0 (f32 + hi/lo straight)
__global__ void enc_init(const float* __restrict__ x, float* __restrict__ hf,
                         u16* __restrict__ hh, u16* __restrict__ hl) {
  int idx = blockIdx.x * 256 + threadIdx.x;
  if (idx >= 65 * ROWS) return;
  int c = idx / ROWS, col = idx % ROWS;
  int b = col >> 8, n = col & 255;
  float v = (c == 0) ? x[(size_t)b * (TLEN * NNODE) + n] : 0.f;
  hf[idx] = v;
  u16 h, l; split2(v, h, l);
  hh[idx] = h; hl[idx] = l;
}

// attention + decoder state init (straight layouts only)
__global__ __launch_bounds__(128) void attn2(const float* __restrict__ hEf,
                                             const float* __restrict__ Wq,
                                             const float* __restrict__ Mem,
                                             float* __restrict__ hDf,
                                             u16* __restrict__ hDh,
                                             u16* __restrict__ hDl) {
  int col = blockIdx.x * 128 + threadIdx.x;
  float h[64];
  for (int c = 0; c < 64; ++c) h[c] = hEf[(size_t)(1 + c) * ROWS + col];
  float q[32];
  for (int j = 0; j < 32; ++j) {
    float s = 0.f;
    for (int c = 0; c < 64; ++c) s = fmaf(h[c], Wq[c * 32 + j], s);
    q[j] = s;
  }
  float l[8], mx = -3.402823466e38f;
  for (int m = 0; m < 8; ++m) {
    float s = 0.f;
    for (int j = 0; j < 32; ++j) s = fmaf(q[j], Mem[m * 32 + j], s);
    l[m] = s;
    mx = fmaxf(mx, s);
  }
  float se = 0.f;
  for (int m = 0; m < 8; ++m) { l[m] = expf(l[m] - mx); se += l[m]; }
  float val[32];
  for (int j = 0; j < 32; ++j) {
    float v = 0.f;
    for (int m = 0; m < 8; ++m) v = fmaf(l[m] / se, Mem[m * 32 + j], v);
    val[j] = v;
  }
  for (int c = 0; c < 97; ++c) {
    float v = (c == 0) ? 0.f : ((c <= 64) ? h[c - 1] : val[c - 65]);
    hDf[(size_t)c * ROWS + col] = v;
    u16 hh, ll; split2(v, hh, ll);
    hDh[(size_t)c * ROWS + col] = hh;
    hDl[(size_t)c * ROWS + col] = ll;
  }
}

// ====================== fused half-step kernel ======================
// Block: 16 cols (one b, 16 consecutive n), 256 threads (4 waves). Grid: 512.
// Phase 1 (GEMM1/sconv): G_p[c][n] = sum_m A[c][(b,m)] * S_p[n][m], p=1..4,
//   A/S fragments direct from global (L2-hot), acc in VGPRs, split2 -> LDS G.
//   LDS slot map: slot=c (c in [1,HID]), slot0 = 0.0, ch0 value -> slot HID+1.
// Phase 2 (GEMM2/wgemm): acc2[o] = sum_p sum_{c in [1,HID)} Wf_p[o][c]*G_p[col][c]
//   (MFMA, K=NKC*32 exact) + rank-1 fixups for c=0 (w0) and c=HID (wlast).
// MODE 0: gate: sigmoid; z*h -> u bufs; r -> rbuf; u ch0 <- state ch0.
// MODE 1: upd-enc: tanh; h' = r*h+(1-r)*hc -> state; ch0 <- x[t+1].
// MODE 2: upd-dec: same + fused proj -> go -> ch0 + out[b][t][n].
template <int C, int HID, int CPAD, int O, int NKC, int MODE>
__global__ __launch_bounds__(256, 2) void fused_step(
    const u16* __restrict__ Ah, const u16* __restrict__ Al,
    const u16* __restrict__ Sh, const u16* __restrict__ Sl,
    const u16* __restrict__ WfH, const u16* __restrict__ WfL,
    const float* __restrict__ w0, const float* __restrict__ wlast,
    const float* __restrict__ bias,
    float* __restrict__ stF, float* __restrict__ rbuf,
    u16* __restrict__ outH, u16* __restrict__ outL,
    const float* __restrict__ xsrc, int tnext,
    const float* __restrict__ pw, const float* __restrict__ pb,
    float* __restrict__ outp, int tcur) {
  constexpr int MT1 = (C + 15) / 16;   // 5 | 7
  constexpr int MI1 = (MT1 + 3) / 4;   // 2
  constexpr int MT2 = O / 16;          // 8|4|12|6
  constexpr int MI2 = (MT2 + 3) / 4;   // 2|1|3|2
  constexpr int CH0SLOT = HID + 1;

  __shared__ __align__(16) u16 Gh[5][16][CPAD];
  __shared__ __align__(16) u16 Gl[5][16][CPAD];
  __shared__ float projL[(MODE == 2) ? 16 : 1][(MODE == 2) ? 100 : 4];

  const int tid = threadIdx.x;
  const int wid = tid >> 6;
  const int lane = tid & 63;
  const int g = lane >> 4, li = lane & 15;
  const int col0 = blockIdx.x * 16;
  const int b = col0 >> 8;
  const int n0 = col0 & 255;
  const int col = col0 + li;

  // ---- stage G_0 from A (p=0 / identity-S piece) ----
  for (int i = tid; i < 16 * C; i += 256) {
    int c = i >> 4, cl = i & 15;
    int slot = (c == 0) ? CH0SLOT : c;
    Gh[0][cl][slot] = Ah[(size_t)c * ROWS + col0 + cl];
    Gl[0][cl][slot] = Al[(size_t)c * ROWS + col0 + cl];
  }
  if (tid < 16) { Gh[0][tid][0] = 0; Gl[0][tid][0] = 0; }

  // ---- GEMM1 ----
  f32x4 acc1[4][MI1];
#pragma unroll
  for (int pp = 0; pp < 4; ++pp)
#pragma unroll
    for (int mi = 0; mi < MI1; ++mi) acc1[pp][mi] = (f32x4){0.f, 0.f, 0.f, 0.f};

#pragma unroll 2
  for (int mc = 0; mc < 8; ++mc) {
    bf16x8 sbh[4], sbl[4];
#pragma unroll
    for (int pp = 0; pp < 4; ++pp) {
      size_t sa = (size_t)pp * 65536 + (size_t)(n0 + li) * 256 + mc * 32 + g * 8;
      sbh[pp] = *(const bf16x8*)(Sh + sa);
      sbl[pp] = *(const bf16x8*)(Sl + sa);
    }
#pragma unroll
    for (int mi = 0; mi < MI1; ++mi) {
      const int mt = wid + mi * 4;
      if (mt < MT1) {
        int c = mt * 16 + li;
        bf16x8 ah = (bf16x8){0, 0, 0, 0, 0, 0, 0, 0};
        bf16x8 al = ah;
        if (c < C) {
          size_t aa = (size_t)c * ROWS + (size_t)b * 256 + mc * 32 + g * 8;
          ah = *(const bf16x8*)(Ah + aa);
          al = *(const bf16x8*)(Al + aa);
        }
#pragma unroll
        for (int pp = 0; pp < 4; ++pp) {
          acc1[pp][mi] = __builtin_amdgcn_mfma_f32_16x16x32_bf16(ah, sbh[pp], acc1[pp][mi], 0, 0, 0);
          acc1[pp][mi] = __builtin_amdgcn_mfma_f32_16x16x32_bf16(ah, sbl[pp], acc1[pp][mi], 0, 0, 0);
          acc1[pp][mi] = __builtin_amdgcn_mfma_f32_16x16x32_bf16(al, sbh[pp], acc1[pp][mi], 0, 0, 0);
        }
      }
    }
  }

  // ---- epi1: split + write G_p to LDS ----
#pragma unroll
  for (int pp = 0; pp < 4; ++pp)
#pragma unroll
    for (int mi = 0; mi < MI1; ++mi) {
      const int mt = wid + mi * 4;
      if (mt < MT1) {
        int cq = mt * 16 + 4 * g;
        u16 h4[4], l4[4];
#pragma unroll
        for (int r = 0; r < 4; ++r) split2(acc1[pp][mi][r], h4[r], l4[r]);
        int p = pp + 1;
        if (cq == 0) {
          Gh[p][li][CH0SLOT] = h4[0];
          Gl[p][li][CH0SLOT] = l4[0];
          h4[0] = 0; l4[0] = 0;
        }
        if (cq + 3 <= HID) {
          uint2 vh, vl;
          vh.x = (uint32_t)h4[0] | ((uint32_t)h4[1] << 16);
          vh.y = (uint32_t)h4[2] | ((uint32_t)h4[3] << 16);
          vl.x = (uint32_t)l4[0] | ((uint32_t)l4[1] << 16);
          vl.y = (uint32_t)l4[2] | ((uint32_t)l4[3] << 16);
          *(uint2*)&Gh[p][li][cq] = vh;
          *(uint2*)&Gl[p][li][cq] = vl;
        } else {
#pragma unroll
          for (int r = 0; r < 4; ++r) {
            int c = cq + r;
            if (c >= 1 && c <= HID) {
              Gh[p][li][c] = h4[r];
              Gl[p][li][c] = l4[r];
            }
          }
        }
      }
    }
  __syncthreads();

  // ---- GEMM2 ----
  f32x4 acc2[MI2];
#pragma unroll
  for (int mi = 0; mi < MI2; ++mi) acc2[mi] = (f32x4){0.f, 0.f, 0.f, 0.f};

#pragma unroll 2
  for (int p = 0; p < 5; ++p) {
    for (int kc = 0; kc < NKC; ++kc) {
      bf16x8 bh = *(const bf16x8*)&Gh[p][li][kc * 32 + g * 8];
      bf16x8 bl = *(const bf16x8*)&Gl[p][li][kc * 32 + g * 8];
#pragma unroll
      for (int mi = 0; mi < MI2; ++mi) {
        const int mt = wid + mi * 4;
        if (mt < MT2) {
          size_t wa = (((size_t)(p * NKC + kc)) * O + mt * 16 + li) * 32 + g * 8;
          bf16x8 wh = *(const bf16x8*)(WfH + wa);
          bf16x8 wl = *(const bf16x8*)(WfL + wa);
          acc2[mi] = __builtin_amdgcn_mfma_f32_16x16x32_bf16(wh, bh, acc2[mi], 0, 0, 0);
          acc2[mi] = __builtin_amdgcn_mfma_f32_16x16x32_bf16(wh, bl, acc2[mi], 0, 0, 0);
          acc2[mi] = __builtin_amdgcn_mfma_f32_16x16x32_bf16(wl, bh, acc2[mi], 0, 0, 0);
        }
      }
    }
  }

  // ---- rank-1 inputs (c=0 and c=HID channels) ----
  float ch0v[5], clv[5];
#pragma unroll
  for (int p = 0; p < 5; ++p) {
    ch0v[p] = (p == 0) ? stF[col]
                       : (bf2f(Gh[p][li][CH0SLOT]) + bf2f(Gl[p][li][CH0SLOT]));
    clv[p] = bf2f(Gh[p][li][HID]) + bf2f(Gl[p][li][HID]);
  }

  // ---- epilogue ----
#pragma unroll
  for (int mi = 0; mi < MI2; ++mi) {
    const int mt = wid + mi * 4;
    if (mt < MT2) {
#pragma unroll
      for (int r = 0; r < 4; ++r) {
        int o = mt * 16 + 4 * g + r;
        float v = acc2[mi][r] + bias[o];
#pragma unroll
        for (int p = 0; p < 5; ++p) {
          v = fmaf(w0[p * O + o], ch0v[p], v);
          v = fmaf(wlast[p * O + o], clv[p], v);
        }
        if (MODE == 0) {
          float s = 1.0f / (1.0f + expf(-v));
          if (o < HID) {
            float u = s * stF[(size_t)(1 + o) * ROWS + col];
            u16 h_, l_; split2(u, h_, l_);
            outH[(size_t)(1 + o) * ROWS + col] = h_;
            outL[(size_t)(1 + o) * ROWS + col] = l_;
          } else {
            rbuf[(size_t)(o - HID) * ROWS + col] = s;
          }
        } else {
          float hc = tanhf(v);
          float hp = stF[(size_t)(1 + o) * ROWS + col];
          float rr = rbuf[(size_t)o * ROWS + col];
          float hn = rr * hp + (1.0f - rr) * hc;
          stF[(size_t)(1 + o) * ROWS + col] = hn;
          u16 h_, l_; split2(hn, h_, l_);
          outH[(size_t)(1 + o) * ROWS + col] = h_;
          outL[(size_t)(1 + o) * ROWS + col] = l_;
          if (MODE == 2) projL[li][o] = hn;
        }
      }
    }
  }

  if (MODE == 0) {
    // u ch0 = state ch0
    if (tid < 16) {
      int cc = col0 + tid;
      u16 h_, l_; split2(stF[cc], h_, l_);
      outH[cc] = h_; outL[cc] = l_;
    }
  }
  if (MODE == 1) {
    __syncthreads();  // all ch0v reads done before ch0 overwrite
    if (tid < 16) {
      int cc = col0 + tid;
      int n = cc & 255;
      float xv = (tnext >= 0)
          ? xsrc[(size_t)b * (TLEN * NNODE) + (size_t)tnext * NNODE + n]
          : stF[cc];
      stF[cc] = xv;
      u16 h_, l_; split2(xv, h_, l_);
      outH[cc] = h_; outL[cc] = l_;
    }
  }
  if (MODE == 2) {
    __syncthreads();  // projL complete + ch0v reads done
    if (tid < 16) {
      int cc = col0 + tid;
      int n = cc & 255;
      float s = pb[0];
#pragma unroll
      for (int o = 0; o < HID; ++o) s = fmaf(pw[o], projL[tid][o], s);
      stF[cc] = s;
      u16 h_, l_; split2(s, h_, l_);
      outH[cc] = h_; outL[cc] = l_;
      outp[((size_t)b * TLEN + tcur) * NNODE + n] = s;
    }
  }
}

// ====================== host launch ======================
extern "C" void kernel_launch(void* const* d_in, const int* in_sizes, int n_in,
                              void* d_out, int out_size, void* d_ws, size_t ws_size,
                              hipStream_t stream) {
  (void)in_sizes; (void)n_in; (void)out_size; (void)ws_size;
  const float* x   = (const float*)d_in[0];
  const float* Mem = (const float*)d_in[1];
  const float* Wq  = (const float*)d_in[2];
  const float* We1 = (const float*)d_in[3];
  const float* We2 = (const float*)d_in[4];
  const float* egw = (const float*)d_in[5];
  const float* egb = (const float*)d_in[6];
  const float* euw = (const float*)d_in[7];
  const float* eub = (const float*)d_in[8];
  const float* dgw = (const float*)d_in[9];
  const float* dgb = (const float*)d_in[10];
  const float* duw = (const float*)d_in[11];
  const float* dub = (const float*)d_in[12];
  const float* pw  = (const float*)d_in[13];
  const float* pb  = (const float*)d_in[14];
  float* out = (float*)d_out;

  float* ws = (float*)d_ws;
  size_t off = 0;
  auto allocf = [&](size_t nf) {
    float* p = ws + off;
    off += (nf + 63) & ~(size_t)63;
    return p;
  };
  auto allocu = [&](size_t nu) { return (u16*)allocf((nu + 1) / 2); };

  float* Sf  = allocf(4 * 65536);
  float* e1  = allocf(8192);
  float* e2  = allocf(8192);
  float* n1  = allocf(256);
  float* n2  = allocf(256);
  float* adj = allocf(65536);
  float* deg = allocf(256);
  int* stats = (int*)allocf(64);
  float* rb  = allocf((size_t)96 * ROWS);
  float* hEf = allocf((size_t)65 * ROWS);
  float* hDf = allocf((size_t)97 * ROWS);
  float* w0gE = allocf(5 * 128);
  float* w0uE = allocf(5 * 64);
  float* w0gD = allocf(5 * 192);
  float* w0uD = allocf(5 * 96);
  float* wlgE = allocf(5 * 128);
  float* wluE = allocf(5 * 64);
  float* wlgD = allocf(5 * 192);
  float* wluD = allocf(5 * 96);

  u16* Sh = allocu(4 * 65536);
  u16* Sl = allocu(4 * 65536);
  u16* hEh = allocu((size_t)65 * ROWS);
  u16* hEl = allocu((size_t)65 * ROWS);
  u16* uEh = allocu((size_t)65 * ROWS);
  u16* uEl = allocu((size_t)65 * ROWS);
  u16* hDh = allocu((size_t)97 * ROWS);
  u16* hDl = allocu((size_t)97 * ROWS);
  u16* uDh = allocu((size_t)97 * ROWS);
  u16* uDl = allocu((size_t)97 * ROWS);
  u16* WgEh = allocu((size_t)5 * 2 * 128 * 32);
  u16* WgEl = allocu((size_t)5 * 2 * 128 * 32);
  u16* WuEh = allocu((size_t)5 * 2 * 64 * 32);
  u16* WuEl = allocu((size_t)5 * 2 * 64 * 32);
  u16* WgDh = allocu((size_t)5 * 3 * 192 * 32);
  u16* WgDl = allocu((size_t)5 * 3 * 192 * 32);
  u16* WuDh = allocu((size_t)5 * 3 * 96 * 32);
  u16* WuDl = allocu((size_t)5 * 3 * 96 * 32);

  // ---- PRNG keys (jax partitionable threefry) ----
  uint32_t ka0, ka1, kb0, kb1;
  tf2x32(0u, 42u, 0u, 0u, &ka0, &ka1);
  tf2x32(0u, 42u, 0u, 1u, &kb0, &kb1);

  // ---- graph setup ----
  setup_embed_kernel<<<1, 256, 0, stream>>>(We1, We2, Mem, e1, e2, n1, n2);
  stats_init_kernel<<<1, 1, 0, stream>>>(stats);
  adj_kernel<<<256, 256, 0, stream>>>(e1, e2, n1, n2, ka0, ka1, adj, deg, stats);
  lap_kernel<<<256, 256, 0, stream>>>(adj, deg, stats, Sf);
  t2_kernel<<<dim3(4, 4), 256, 0, stream>>>(Sf, Sf + 65536);
  stats_init_kernel<<<1, 1, 0, stream>>>(stats);
  adj_kernel<<<256, 256, 0, stream>>>(e2, e1, n2, n1, kb0, kb1, adj, deg, stats);
  lap_kernel<<<256, 256, 0, stream>>>(adj, deg, stats, Sf + 2 * 65536);
  t2_kernel<<<dim3(4, 4), 256, 0, stream>>>(Sf + 2 * 65536, Sf + 3 * 65536);
  cvt_s_kernel<<<1024, 256, 0, stream>>>(Sf, Sh, Sl);
  build_wfrag<<<(5 * 64 * 128 + 255) / 256, 256, 0, stream>>>(egw, 65, 128, 64, WgEh, WgEl, w0gE, wlgE);
  build_wfrag<<<(5 * 64 * 64 + 255) / 256, 256, 0, stream>>>(euw, 65, 64, 64, WuEh, WuEl, w0uE, wluE);
  build_wfrag<<<(5 * 96 * 192 + 255) / 256, 256, 0, stream>>>(dgw, 97, 192, 96, WgDh, WgDl, w0gD, wlgD);
  build_wfrag<<<(5 * 96 * 96 + 255) / 256, 256, 0, stream>>>(duw, 97, 96, 96, WuDh, WuDl, w0uD, wluD);

  // ---- encoder ----
  enc_init<<<(65 * ROWS + 255) / 256, 256, 0, stream>>>(x, hEf, hEh, hEl);
  for (int t = 0; t < TLEN; ++t) {
    fused_step<65, 64, 72, 128, 2, 0><<<512, 256, 0, stream>>>(
        hEh, hEl, Sh, Sl, WgEh, WgEl, w0gE, wlgE, egb, hEf, rb, uEh, uEl,
        nullptr, -1, nullptr, nullptr, nullptr, 0);
    fused_step<65, 64, 72, 64, 2, 1><<<512, 256, 0, stream>>>(
        uEh, uEl, Sh, Sl, WuEh, WuEl, w0uE, wluE, eub, hEf, rb, hEh, hEl,
        x, (t + 1 < TLEN) ? (t + 1) : -1, nullptr, nullptr, nullptr, 0);
  }

  // ---- attention + decoder init ----
  attn2<<<64, 128, 0, stream>>>(hEf, Wq, Mem, hDf, hDh, hDl);

  // ---- decoder ----
  for (int t = 0; t < TLEN; ++t) {
    fused_step<97, 96, 104, 192, 3, 0><<<512, 256, 0, stream>>>(
        hDh, hDl, Sh, Sl, WgDh, WgDl, w0gD, wlgD, dgb, hDf, rb, uDh, uDl,
        nullptr, -1, nullptr, nullptr, nullptr, 0);
    fused_step<97, 96, 104, 96, 3, 2><<<512, 256, 0, stream>>>(
        uDh, uDl, Sh, Sl, WuDh, WuDl, w0uD, wluD, dub, hDf, rb, hDh, hDl,
        nullptr, -1, pw, pb, out, t);
  }
}

// Round 4
// 12221.481 us; speedup vs baseline: 5.2468x; 1.6133x over previous
//
#include <hip/hip_runtime.h>
#include <stdint.h>
#include <math.h>

// ====================== problem constants ======================
#define NNODE 256
#define BATCH 32
#define TLEN  128
#define ROWS  8192 // NNODE*BATCH

typedef unsigned short u16;
typedef short bf16x8 __attribute__((ext_vector_type(8)));
typedef float f32x4 __attribute__((ext_vector_type(4)));

__device__ inline u16 f2bf_rn(float v) {
  uint32_t u = __float_as_uint(v);
  u += 0x7fffu + ((u >> 16) & 1u);
  return (u16)(u >> 16);
}
__device__ inline float bf2f(u16 h) { return __uint_as_float(((uint32_t)h) << 16); }
__device__ inline void split2(float v, u16& hi, u16& lo) {
  hi = f2bf_rn(v);
  lo = f2bf_rn(v - bf2f(hi));
}

// packed-state element address: fragment (ct=c/16, b, mc=n/32), lane-major
__device__ inline size_t pk_addr(int c, int b, int n) {
  return ((((size_t)(c >> 4) * 32 + b) * 8 + (n >> 5)) << 9) +
         (((size_t)((c & 15) | (((n >> 3) & 3) << 4))) << 3) + (n & 7);
}

// ====================== Threefry-2x32 (20 rounds) ======================
__host__ __device__ inline uint32_t rotl32_(uint32_t v, int d) {
  return (v << d) | (v >> (32 - d));
}
__host__ __device__ inline void tf2x32(uint32_t k0, uint32_t k1, uint32_t x0,
                                       uint32_t x1, uint32_t* o0, uint32_t* o1) {
  uint32_t ks2 = k0 ^ k1 ^ 0x1BD11BDAu;
  x0 += k0; x1 += k1;
  x0 += x1; x1 = rotl32_(x1, 13); x1 ^= x0;
  x0 += x1; x1 = rotl32_(x1, 15); x1 ^= x0;
  x0 += x1; x1 = rotl32_(x1, 26); x1 ^= x0;
  x0 += x1; x1 = rotl32_(x1, 6);  x1 ^= x0;
  x0 += k1; x1 += ks2 + 1u;
  x0 += x1; x1 = rotl32_(x1, 17); x1 ^= x0;
  x0 += x1; x1 = rotl32_(x1, 29); x1 ^= x0;
  x0 += x1; x1 = rotl32_(x1, 16); x1 ^= x0;
  x0 += x1; x1 = rotl32_(x1, 24); x1 ^= x0;
  x0 += ks2; x1 += k0 + 2u;
  x0 += x1; x1 = rotl32_(x1, 13); x1 ^= x0;
  x0 += x1; x1 = rotl32_(x1, 15); x1 ^= x0;
  x0 += x1; x1 = rotl32_(x1, 26); x1 ^= x0;
  x0 += x1; x1 = rotl32_(x1, 6);  x1 ^= x0;
  x0 += k0; x1 += k1 + 3u;
  x0 += x1; x1 = rotl32_(x1, 17); x1 ^= x0;
  x0 += x1; x1 = rotl32_(x1, 29); x1 ^= x0;
  x0 += x1; x1 = rotl32_(x1, 16); x1 ^= x0;
  x0 += x1; x1 = rotl32_(x1, 24); x1 ^= x0;
  x0 += k1; x1 += ks2 + 4u;
  x0 += x1; x1 = rotl32_(x1, 13); x1 ^= x0;
  x0 += x1; x1 = rotl32_(x1, 15); x1 ^= x0;
  x0 += x1; x1 = rotl32_(x1, 26); x1 ^= x0;
  x0 += x1; x1 = rotl32_(x1, 6);  x1 ^= x0;
  x0 += ks2; x1 += k0 + 5u;
  *o0 = x0; *o1 = x1;
}

__device__ inline float gumbel_at(uint32_t k0, uint32_t k1, uint32_t idx) {
  uint32_t o0, o1;
  tf2x32(k0, k1, 0u, idx, &o0, &o1);
  uint32_t b = o0 ^ o1;
  float f = __uint_as_float((b >> 9) | 0x3f800000u) - 1.0f;
  const float tiny = 1.17549435e-38f;
  float u = fmaxf(tiny, f + tiny);
  return -logf(-logf(u));
}

// ====================== graph setup kernels (fp32, one-time) ======================
__global__ __launch_bounds__(256) void setup_embed_kernel(
    const float* __restrict__ We1, const float* __restrict__ We2,
    const float* __restrict__ Mem, float* __restrict__ e1, float* __restrict__ e2,
    float* __restrict__ n1, float* __restrict__ n2) {
  int n = threadIdx.x;
  float a[8];
  float s;
  for (int m = 0; m < 8; ++m) a[m] = We1[n * 8 + m];
  s = 0.f;
  for (int j = 0; j < 32; ++j) {
    float v = 0.f;
    for (int m = 0; m < 8; ++m) v = fmaf(a[m], Mem[m * 32 + j], v);
    e1[n * 32 + j] = v;
    s = fmaf(v, v, s);
  }
  n1[n] = sqrtf(s);
  for (int m = 0; m < 8; ++m) a[m] = We2[n * 8 + m];
  s = 0.f;
  for (int j = 0; j < 32; ++j) {
    float v = 0.f;
    for (int m = 0; m < 8; ++m) v = fmaf(a[m], Mem[m * 32 + j], v);
    e2[n * 32 + j] = v;
    s = fmaf(v, v, s);
  }
  n2[n] = sqrtf(s);
}

__global__ void stats_init_kernel(int* stats) {
  stats[0] = 0;
  stats[1] = 0;
  stats[2] = 0x7fffffff;
}

__global__ __launch_bounds__(256) void adj_kernel(
    const float* __restrict__ eA, const float* __restrict__ eB,
    const float* __restrict__ nA, const float* __restrict__ nB,
    uint32_t k0, uint32_t k1, float* __restrict__ adj, float* __restrict__ deg,
    int* __restrict__ stats) {
  int i = blockIdx.x, j = threadIdx.x;
  float dot = 0.f;
  for (int c = 0; c < 32; ++c) dot = fmaf(eA[i * 32 + c], eB[j * 32 + c], dot);
  float g = dot / (nA[i] * nB[j] + 1e-6f);
  g = (g + 1.0f) * 0.5f;
  uint32_t f = ((uint32_t)(i * 256 + j)) * 2u;
  float g0 = gumbel_at(k0, k1, f);
  float g1 = gumbel_at(k0, k1, f + 1u);
  float a = ((g + g0) >= ((1.0f - g) + g1)) ? 1.0f : 0.0f;
  if (i == j) a = 0.0f;
  adj[i * 256 + j] = a;
  __shared__ float red[256];
  red[j] = a;
  __syncthreads();
  for (int s = 128; s > 0; s >>= 1) {
    if (j < s) red[j] += red[j + s];
    __syncthreads();
  }
  if (j == 0) {
    float d = red[0];
    deg[i] = d;
    atomicMax(&stats[0], (int)d);
    atomicMin(&stats[2], (int)d);
    if (d > 0.5f) atomicOr(&stats[1], 1);
  }
}

__global__ __launch_bounds__(256) void lap_kernel(const float* __restrict__ adj,
                                                  const float* __restrict__ deg,
                                                  const int* __restrict__ stats,
                                                  float* __restrict__ S1) {
  int i = blockIdx.x, j = threadIdx.x;
  float lmax = (float)stats[0];
  float lmin = stats[1] ? -1.0f : (float)stats[2];
  float lam = lmax - lmin;
  float L = (i == j) ? deg[i] : -adj[i * 256 + j];
  S1[i * 256 + j] = 2.0f * L / lam - ((i == j) ? 1.0f : 0.0f);
}

// T2 = 2*(S1@S1) - I  (fp32 VALU tile GEMM, one-time)
__global__ __launch_bounds__(256) void t2_kernel(const float* __restrict__ A,
                                                 float* __restrict__ Cout) {
  __shared__ __align__(16) float sAT[32][68];
  __shared__ __align__(16) float sB[32][68];
  int tid = threadIdx.x;
  int tc = tid & 15, tr = tid >> 4;
  int row0 = blockIdx.y * 64, col0 = blockIdx.x * 64;
  float acc[4][4] = {};
  for (int m0 = 0; m0 < 256; m0 += 32) {
    for (int i = tid; i < 2048; i += 256) {
      int r = i >> 5, c = i & 31;
      sAT[c][r] = A[(size_t)(row0 + r) * 256 + m0 + c];
    }
    for (int i = tid; i < 2048; i += 256) {
      int r = i >> 6, c = i & 63;
      sB[r][c] = A[(size_t)(m0 + r) * 256 + col0 + c];
    }
    __syncthreads();
#pragma unroll
    for (int kk = 0; kk < 32; ++kk) {
      float4 av = *(const float4*)&sAT[kk][tr * 4];
      float4 bv = *(const float4*)&sB[kk][tc * 4];
      float a[4] = {av.x, av.y, av.z, av.w};
      float b[4] = {bv.x, bv.y, bv.z, bv.w};
#pragma unroll
      for (int i = 0; i < 4; ++i)
#pragma unroll
        for (int j = 0; j < 4; ++j) acc[i][j] = fmaf(a[i], b[j], acc[i][j]);
    }
    __syncthreads();
  }
#pragma unroll
  for (int i = 0; i < 4; ++i) {
    int row = row0 + tr * 4 + i;
#pragma unroll
    for (int j = 0; j < 4; ++j) {
      int col = col0 + tc * 4 + j;
      Cout[(size_t)row * 256 + col] = 2.0f * acc[i][j] - ((row == col) ? 1.0f : 0.0f);
    }
  }
}

// S fp32 -> fragment-packed hi/lo bf16
__global__ void cvt_s_packed(const float* __restrict__ S, u16* __restrict__ Sh,
                             u16* __restrict__ Sl) {
  int idx = blockIdx.x * 256 + threadIdx.x;
  if (idx >= 4 * 65536) return;
  int p = idx >> 16, rem = idx & 65535;
  int n = rem >> 8, m = rem & 255;
  int nt = n >> 4, li = n & 15;
  int mc = m >> 5, g = (m >> 3) & 3, j = m & 7;
  int lane = li | (g << 4);
  size_t a = (((size_t)(p * 16 + nt) * 8 + mc) << 9) + lane * 8 + j;
  u16 h, l;
  split2(S[idx], h, l);
  Sh[a] = h; Sl[a] = l;
}

// W fragment-packed: frag(p,kc,ot), element(lane,j) = W[(korig*C + c)*O + o],
// c = kc*32 + (lane>>4)*8 + j, o = ot*16 + (lane&15); c==0 zeroed (rank-1 w0),
// c==hid excluded (rank-1 wlast). Fold k=3 into p=0 (Chebyshev identity).
__global__ void build_wfrag(const float* __restrict__ W, int C, int O, int hid,
                            u16* __restrict__ WfH, u16* __restrict__ WfL,
                            float* __restrict__ w0, float* __restrict__ wlast) {
  int idx = blockIdx.x * 256 + threadIdx.x;
  int nKC = hid / 32;
  if (idx < 5 * hid * O) {
    int kk = idx & 31;
    int rest = idx >> 5;
    int o = rest % O; rest /= O;
    int kc = rest % nKC;
    int p = rest / nKC;
    int korig = (p == 0) ? 0 : (p + (p >= 3 ? 1 : 0));
    int c = kc * 32 + kk;
    float v = 0.f;
    if (c > 0) {
      v = W[(size_t)(korig * C + c) * O + o];
      if (p == 0) v += W[(size_t)(3 * C + c) * O + o];
    }
    int ot = o >> 4, li = o & 15, g = kk >> 3, j = kk & 7;
    int lane = li | (g << 4);
    size_t a = (((size_t)(p * nKC + kc) * (O / 16) + ot) << 9) + lane * 8 + j;
    u16 h, l; split2(v, h, l);
    WfH[a] = h; WfL[a] = l;
  }
  if (idx < 5 * O) {
    int o = idx % O, p = idx / O;
    int korig = (p == 0) ? 0 : (p + (p >= 3 ? 1 : 0));
    float v0 = W[(size_t)(korig * C + 0) * O + o];
    if (p == 0) v0 += W[(size_t)(3 * C + 0) * O + o];
    w0[p * O + o] = v0;
    float vl = W[(size_t)(korig * C + hid) * O + o];
    if (p == 0) vl += W[(size_t)(3 * C + hid) * O + o];
    wlast[p * O + o] = vl;
  }
}

__global__ void zero_kernel(uint4* __restrict__ p, int n4) {
  for (int i = blockIdx.x * blockDim.x + threadIdx.x; i < n4;
       i += gridDim.x * blockDim.x)
    p[i] = make_uint4(0, 0, 0, 0);
}

// encoder state init: ch0 = x[:,0], rest 0 (f32 straight + packed ch0)
__global__ void enc_init(const float* __restrict__ x, float* __restrict__ hf,
                         u16* __restrict__ pkh, u16* __restrict__ pkl) {
  int idx = blockIdx.x * 256 + threadIdx.x;
  if (idx >= 65 * ROWS) return;
  int c = idx / ROWS, col = idx % ROWS;
  int b = col >> 8, n = col & 255;
  float v = (c == 0) ? x[(size_t)b * (TLEN * NNODE) + n] : 0.f;
  hf[idx] = v;
  if (c == 0) {
    u16 h, l; split2(v, h, l);
    size_t a = pk_addr(0, b, n);
    pkh[a] = h; pkl[a] = l;
  }
}

// attention + decoder state init (f32 straight + packed)
__global__ __launch_bounds__(128) void attn2(const float* __restrict__ hEf,
                                             const float* __restrict__ Wq,
                                             const float* __restrict__ Mem,
                                             float* __restrict__ hDf,
                                             u16* __restrict__ pkh,
                                             u16* __restrict__ pkl) {
  int col = blockIdx.x * 128 + threadIdx.x;
  int b = col >> 8, n = col & 255;
  float h[64];
  for (int c = 0; c < 64; ++c) h[c] = hEf[(size_t)(1 + c) * ROWS + col];
  float q[32];
  for (int j = 0; j < 32; ++j) {
    float s = 0.f;
    for (int c = 0; c < 64; ++c) s = fmaf(h[c], Wq[c * 32 + j], s);
    q[j] = s;
  }
  float l[8], mx = -3.402823466e38f;
  for (int m = 0; m < 8; ++m) {
    float s = 0.f;
    for (int j = 0; j < 32; ++j) s = fmaf(q[j], Mem[m * 32 + j], s);
    l[m] = s;
    mx = fmaxf(mx, s);
  }
  float se = 0.f;
  for (int m = 0; m < 8; ++m) { l[m] = expf(l[m] - mx); se += l[m]; }
  float val[32];
  for (int j = 0; j < 32; ++j) {
    float v = 0.f;
    for (int m = 0; m < 8; ++m) v = fmaf(l[m] / se, Mem[m * 32 + j], v);
    val[j] = v;
  }
  for (int c = 0; c < 97; ++c) {
    float v = (c == 0) ? 0.f : ((c <= 64) ? h[c - 1] : val[c - 65]);
    hDf[(size_t)c * ROWS + col] = v;
    u16 hh, ll; split2(v, hh, ll);
    size_t a = pk_addr(c, b, n);
    pkh[a] = hh; pkl[a] = ll;
  }
}

// ====================== fused half-step kernel ======================
// Block: 32 cols (one b, two 16-n groups), 512 threads (8 waves: cg=wid>>2,
// set=wid&3). Grid: 256 (1 block/CU).
// GEMM1 (sconv): G_p[c][n] = sum_m A[c][(b,m)] * S_p[n][m], p=1..4. A from
//   fragment-packed state (coalesced), S fragment-packed (coalesced). acc in
//   VGPRs, split2 -> LDS G (slot=c; ch0 -> CH0SLOT; slot0 = 0).
// GEMM2 (wgemm): acc2[o] = sum_p sum_{c in [1,HID)} Wf_p[o][c]*G_p[col][c]
//   (W fragment-packed, coalesced) + rank-1 fixups c=0 (w0) and c=HID (wlast).
// MODE 0: gate: sigmoid; z*h -> outF f32 + packed; r -> rbuf; ch0 copy.
// MODE 1: upd-enc: tanh; h' = r*h+(1-r)*hc -> HF + packed; ch0 <- x[t+1].
// MODE 2: upd-dec: same + fused proj -> go -> ch0 + out[b][t][n].
template <int C, int HID, int CPAD, int O, int NKC, int MT1, int MODE>
__global__ __launch_bounds__(512) void fused_step(
    const float* __restrict__ AF,
    const u16* __restrict__ ApkH, const u16* __restrict__ ApkL,
    const u16* __restrict__ SpkH, const u16* __restrict__ SpkL,
    const u16* __restrict__ WpkH, const u16* __restrict__ WpkL,
    const float* __restrict__ w0, const float* __restrict__ wlast,
    const float* __restrict__ bias,
    float* __restrict__ HF, float* __restrict__ outF,
    u16* __restrict__ outPkH, u16* __restrict__ outPkL,
    float* __restrict__ rbuf,
    const float* __restrict__ xsrc, int tnext,
    const float* __restrict__ pw, const float* __restrict__ pb,
    float* __restrict__ outp, int tcur) {
  constexpr int MT2 = O / 16;
  constexpr int MI1 = 2;
  constexpr int MI2 = (MT2 + 3) / 4;
  constexpr int CH0SLOT = HID + 1;

  __shared__ __align__(16) u16 Gh[2][5][16][CPAD];
  __shared__ __align__(16) u16 Gl[2][5][16][CPAD];
  __shared__ float projL[(MODE == 2) ? 2 : 1][16][(MODE == 2) ? 100 : 1];

  const int tid = threadIdx.x;
  const int wid = tid >> 6, lane = tid & 63;
  const int g = lane >> 4, li = lane & 15;
  const int cg = wid >> 2, set = wid & 3;
  const int col0 = blockIdx.x * 32;
  const int b = col0 >> 8;
  const int n0 = (col0 & 255) + cg * 16;
  const int nt = n0 >> 4;
  const int col = col0 + cg * 16 + li;

  // ---- stage G_0 from f32 state (identity-S piece) ----
  for (int i = tid; i < 32 * C; i += 512) {
    int c = i >> 5, q = i & 31;
    float v = AF[(size_t)c * ROWS + col0 + q];
    u16 h, l; split2(v, h, l);
    int slot = (c == 0) ? CH0SLOT : c;
    Gh[q >> 4][0][q & 15][slot] = h;
    Gl[q >> 4][0][q & 15][slot] = l;
  }
  if (tid < 32) {
    Gh[tid >> 4][0][tid & 15][0] = 0;
    Gl[tid >> 4][0][tid & 15][0] = 0;
  }

  // ---- GEMM1 (all loads coalesced fragment-packed) ----
  f32x4 acc1[4][MI1];
#pragma unroll
  for (int pp = 0; pp < 4; ++pp)
#pragma unroll
    for (int mi = 0; mi < MI1; ++mi) acc1[pp][mi] = (f32x4){0.f, 0.f, 0.f, 0.f};

#pragma unroll 2
  for (int mc = 0; mc < 8; ++mc) {
    bf16x8 sbh[4], sbl[4];
#pragma unroll
    for (int pp = 0; pp < 4; ++pp) {
      size_t sa = (((size_t)(pp * 16 + nt) * 8 + mc) << 9) + lane * 8;
      sbh[pp] = *(const bf16x8*)(SpkH + sa);
      sbl[pp] = *(const bf16x8*)(SpkL + sa);
    }
#pragma unroll
    for (int mi = 0; mi < MI1; ++mi) {
      const int mt = set + mi * 4;
      if (mt < MT1) {
        size_t aa = (((size_t)(mt * 32 + b) * 8 + mc) << 9) + lane * 8;
        bf16x8 ah = *(const bf16x8*)(ApkH + aa);
        bf16x8 al = *(const bf16x8*)(ApkL + aa);
#pragma unroll
        for (int pp = 0; pp < 4; ++pp) {
          acc1[pp][mi] = __builtin_amdgcn_mfma_f32_16x16x32_bf16(ah, sbh[pp], acc1[pp][mi], 0, 0, 0);
          acc1[pp][mi] = __builtin_amdgcn_mfma_f32_16x16x32_bf16(ah, sbl[pp], acc1[pp][mi], 0, 0, 0);
          acc1[pp][mi] = __builtin_amdgcn_mfma_f32_16x16x32_bf16(al, sbh[pp], acc1[pp][mi], 0, 0, 0);
        }
      }
    }
  }

  // ---- epi1: split + write G_p to LDS ----
#pragma unroll
  for (int pp = 0; pp < 4; ++pp)
#pragma unroll
    for (int mi = 0; mi < MI1; ++mi) {
      const int mt = set + mi * 4;
      if (mt < MT1) {
        int cq = mt * 16 + 4 * g;
        u16 h4[4], l4[4];
#pragma unroll
        for (int r = 0; r < 4; ++r) split2(acc1[pp][mi][r], h4[r], l4[r]);
        int p = pp + 1;
        if (cq == 0) {
          Gh[cg][p][li][CH0SLOT] = h4[0];
          Gl[cg][p][li][CH0SLOT] = l4[0];
          h4[0] = 0; l4[0] = 0;
        }
        if (cq + 3 <= HID) {
          uint2 vh, vl;
          vh.x = (uint32_t)h4[0] | ((uint32_t)h4[1] << 16);
          vh.y = (uint32_t)h4[2] | ((uint32_t)h4[3] << 16);
          vl.x = (uint32_t)l4[0] | ((uint32_t)l4[1] << 16);
          vl.y = (uint32_t)l4[2] | ((uint32_t)l4[3] << 16);
          *(uint2*)&Gh[cg][p][li][cq] = vh;
          *(uint2*)&Gl[cg][p][li][cq] = vl;
        } else {
#pragma unroll
          for (int r = 0; r < 4; ++r) {
            int c = cq + r;
            if (c >= 1 && c <= HID) {
              Gh[cg][p][li][c] = h4[r];
              Gl[cg][p][li][c] = l4[r];
            }
          }
        }
      }
    }
  __syncthreads();

  // ---- GEMM2 ----
  f32x4 acc2[MI2];
#pragma unroll
  for (int mi = 0; mi < MI2; ++mi) acc2[mi] = (f32x4){0.f, 0.f, 0.f, 0.f};

#pragma unroll
  for (int p = 0; p < 5; ++p) {
#pragma unroll
    for (int kc = 0; kc < NKC; ++kc) {
      bf16x8 bh = *(const bf16x8*)&Gh[cg][p][li][kc * 32 + g * 8];
      bf16x8 bl = *(const bf16x8*)&Gl[cg][p][li][kc * 32 + g * 8];
#pragma unroll
      for (int mi = 0; mi < MI2; ++mi) {
        const int mt = set + mi * 4;
        if (mt < MT2) {
          size_t wa = (((size_t)(p * NKC + kc) * MT2 + mt) << 9) + lane * 8;
          bf16x8 wh = *(const bf16x8*)(WpkH + wa);
          bf16x8 wl = *(const bf16x8*)(WpkL + wa);
          acc2[mi] = __builtin_amdgcn_mfma_f32_16x16x32_bf16(wh, bh, acc2[mi], 0, 0, 0);
          acc2[mi] = __builtin_amdgcn_mfma_f32_16x16x32_bf16(wh, bl, acc2[mi], 0, 0, 0);
          acc2[mi] = __builtin_amdgcn_mfma_f32_16x16x32_bf16(wl, bh, acc2[mi], 0, 0, 0);
        }
      }
    }
  }

  // ---- rank-1 inputs (c=0 and c=HID channels) ----
  float ch0v[5], clv[5];
#pragma unroll
  for (int p = 0; p < 5; ++p) {
    ch0v[p] = (p == 0) ? AF[col]
                       : (bf2f(Gh[cg][p][li][CH0SLOT]) + bf2f(Gl[cg][p][li][CH0SLOT]));
    clv[p] = bf2f(Gh[cg][p][li][HID]) + bf2f(Gl[cg][p][li][HID]);
  }

  const int ncol = col & 255;

  // ---- epilogue ----
#pragma unroll
  for (int mi = 0; mi < MI2; ++mi) {
    const int mt = set + mi * 4;
    if (mt < MT2) {
#pragma unroll
      for (int r = 0; r < 4; ++r) {
        int o = mt * 16 + 4 * g + r;
        float v = acc2[mi][r] + bias[o];
#pragma unroll
        for (int p = 0; p < 5; ++p) {
          v = fmaf(w0[p * O + o], ch0v[p], v);
          v = fmaf(wlast[p * O + o], clv[p], v);
        }
        if (MODE == 0) {
          float s = 1.0f / (1.0f + expf(-v));
          if (o < HID) {
            float u = s * HF[(size_t)(1 + o) * ROWS + col];
            outF[(size_t)(1 + o) * ROWS + col] = u;
            u16 h_, l_; split2(u, h_, l_);
            size_t a = pk_addr(1 + o, b, ncol);
            outPkH[a] = h_; outPkL[a] = l_;
          } else {
            rbuf[(size_t)(o - HID) * ROWS + col] = s;
          }
        } else {
          float hc = tanhf(v);
          float hp = HF[(size_t)(1 + o) * ROWS + col];
          float rr = rbuf[(size_t)o * ROWS + col];
          float hn = rr * hp + (1.0f - rr) * hc;
          HF[(size_t)(1 + o) * ROWS + col] = hn;
          u16 h_, l_; split2(hn, h_, l_);
          size_t a = pk_addr(1 + o, b, ncol);
          outPkH[a] = h_; outPkL[a] = l_;
          if (MODE == 2) projL[cg][li][o] = hn;
        }
      }
    }
  }

  if (MODE == 0) {
    // u ch0 = input ch0 (x or go)
    if (tid < 32) {
      int cc = col0 + tid;
      float x0 = AF[cc];
      outF[cc] = x0;
      u16 h_, l_; split2(x0, h_, l_);
      size_t a = pk_addr(0, b, cc & 255);
      outPkH[a] = h_; outPkL[a] = l_;
    }
  }
  if (MODE == 1) {
    if (tid < 32) {
      int cc = col0 + tid;
      int n = cc & 255;
      float xv = (tnext >= 0)
          ? xsrc[(size_t)b * (TLEN * NNODE) + (size_t)tnext * NNODE + n]
          : HF[cc];
      HF[cc] = xv;
      u16 h_, l_; split2(xv, h_, l_);
      size_t a = pk_addr(0, b, n);
      outPkH[a] = h_; outPkL[a] = l_;
    }
  }
  if (MODE == 2) {
    __syncthreads();  // projL complete
    if (tid < 32) {
      int cc = col0 + tid;
      int n = cc & 255;
      float s = pb[0];
#pragma unroll
      for (int o = 0; o < HID; ++o) s = fmaf(pw[o], projL[tid >> 4][tid & 15][o], s);
      HF[cc] = s;
      u16 h_, l_; split2(s, h_, l_);
      size_t a = pk_addr(0, b, n);
      outPkH[a] = h_; outPkL[a] = l_;
      outp[((size_t)b * TLEN + tcur) * NNODE + n] = s;
    }
  }
}

// ====================== host launch ======================
extern "C" void kernel_launch(void* const* d_in, const int* in_sizes, int n_in,
                              void* d_out, int out_size, void* d_ws, size_t ws_size,
                              hipStream_t stream) {
  (void)in_sizes; (void)n_in; (void)out_size; (void)ws_size;
  const float* x   = (const float*)d_in[0];
  const float* Mem = (const float*)d_in[1];
  const float* Wq  = (const float*)d_in[2];
  const float* We1 = (const float*)d_in[3];
  const float* We2 = (const float*)d_in[4];
  const float* egw = (const float*)d_in[5];
  const float* egb = (const float*)d_in[6];
  const float* euw = (const float*)d_in[7];
  const float* eub = (const float*)d_in[8];
  const float* dgw = (const float*)d_in[9];
  const float* dgb = (const float*)d_in[10];
  const float* duw = (const float*)d_in[11];
  const float* dub = (const float*)d_in[12];
  const float* pw  = (const float*)d_in[13];
  const float* pb  = (const float*)d_in[14];
  float* out = (float*)d_out;

  float* ws = (float*)d_ws;
  size_t off = 0;
  auto allocf = [&](size_t nf) {
    float* p = ws + off;
    off += (nf + 63) & ~(size_t)63;
    return p;
  };
  auto allocu = [&](size_t nu) { return (u16*)allocf((nu + 1) / 2); };

  float* Sf  = allocf(4 * 65536);
  float* e1  = allocf(8192);
  float* e2  = allocf(8192);
  float* n1  = allocf(256);
  float* n2  = allocf(256);
  float* adj = allocf(65536);
  float* deg = allocf(256);
  int* stats = (int*)allocf(64);
  float* rb  = allocf((size_t)96 * ROWS);
  float* hEf = allocf((size_t)65 * ROWS);
  float* uEf = allocf((size_t)65 * ROWS);
  float* hDf = allocf((size_t)97 * ROWS);
  float* uDf = allocf((size_t)97 * ROWS);
  float* w0gE = allocf(5 * 128);
  float* w0uE = allocf(5 * 64);
  float* w0gD = allocf(5 * 192);
  float* w0uD = allocf(5 * 96);
  float* wlgE = allocf(5 * 128);
  float* wluE = allocf(5 * 64);
  float* wlgD = allocf(5 * 192);
  float* wluD = allocf(5 * 96);

  u16* SpkH = allocu((size_t)4 * 65536);
  u16* SpkL = allocu((size_t)4 * 65536);
  u16* WgEh = allocu((size_t)5 * 2 * 8 * 512);
  u16* WgEl = allocu((size_t)5 * 2 * 8 * 512);
  u16* WuEh = allocu((size_t)5 * 2 * 4 * 512);
  u16* WuEl = allocu((size_t)5 * 2 * 4 * 512);
  u16* WgDh = allocu((size_t)5 * 3 * 12 * 512);
  u16* WgDl = allocu((size_t)5 * 3 * 12 * 512);
  u16* WuDh = allocu((size_t)5 * 3 * 6 * 512);
  u16* WuDl = allocu((size_t)5 * 3 * 6 * 512);

  // packed states — contiguous for one-shot zero init
  const size_t PKE = (size_t)5 * 32 * 8 * 512;   // 655360 u16
  const size_t PKD = (size_t)7 * 32 * 8 * 512;   // 917504 u16
  u16* hEpkH = allocu(PKE);
  u16* hEpkL = allocu(PKE);
  u16* uEpkH = allocu(PKE);
  u16* uEpkL = allocu(PKE);
  u16* hDpkH = allocu(PKD);
  u16* hDpkL = allocu(PKD);
  u16* uDpkH = allocu(PKD);
  u16* uDpkL = allocu(PKD);
  const size_t PKTOT = 4 * PKE + 4 * PKD;        // 6291456 u16

  // ---- PRNG keys (jax partitionable threefry) ----
  uint32_t ka0, ka1, kb0, kb1;
  tf2x32(0u, 42u, 0u, 0u, &ka0, &ka1);
  tf2x32(0u, 42u, 0u, 1u, &kb0, &kb1);

  // ---- init + graph setup ----
  zero_kernel<<<1024, 256, 0, stream>>>((uint4*)hEpkH, (int)(PKTOT / 8));
  setup_embed_kernel<<<1, 256, 0, stream>>>(We1, We2, Mem, e1, e2, n1, n2);
  stats_init_kernel<<<1, 1, 0, stream>>>(stats);
  adj_kernel<<<256, 256, 0, stream>>>(e1, e2, n1, n2, ka0, ka1, adj, deg, stats);
  lap_kernel<<<256, 256, 0, stream>>>(adj, deg, stats, Sf);
  t2_kernel<<<dim3(4, 4), 256, 0, stream>>>(Sf, Sf + 65536);
  stats_init_kernel<<<1, 1, 0, stream>>>(stats);
  adj_kernel<<<256, 256, 0, stream>>>(e2, e1, n2, n1, kb0, kb1, adj, deg, stats);
  lap_kernel<<<256, 256, 0, stream>>>(adj, deg, stats, Sf + 2 * 65536);
  t2_kernel<<<dim3(4, 4), 256, 0, stream>>>(Sf + 2 * 65536, Sf + 3 * 65536);
  cvt_s_packed<<<1024, 256, 0, stream>>>(Sf, SpkH, SpkL);
  build_wfrag<<<(5 * 64 * 128 + 255) / 256, 256, 0, stream>>>(egw, 65, 128, 64, WgEh, WgEl, w0gE, wlgE);
  build_wfrag<<<(5 * 64 * 64 + 255) / 256, 256, 0, stream>>>(euw, 65, 64, 64, WuEh, WuEl, w0uE, wluE);
  build_wfrag<<<(5 * 96 * 192 + 255) / 256, 256, 0, stream>>>(dgw, 97, 192, 96, WgDh, WgDl, w0gD, wlgD);
  build_wfrag<<<(5 * 96 * 96 + 255) / 256, 256, 0, stream>>>(duw, 97, 96, 96, WuDh, WuDl, w0uD, wluD);

  // ---- encoder ----
  enc_init<<<(65 * ROWS + 255) / 256, 256, 0, stream>>>(x, hEf, hEpkH, hEpkL);
  for (int t = 0; t < TLEN; ++t) {
    fused_step<65, 64, 72, 128, 2, 5, 0><<<256, 512, 0, stream>>>(
        hEf, hEpkH, hEpkL, SpkH, SpkL, WgEh, WgEl, w0gE, wlgE, egb,
        hEf, uEf, uEpkH, uEpkL, rb, nullptr, -1, nullptr, nullptr, nullptr, 0);
    fused_step<65, 64, 72, 64, 2, 5, 1><<<256, 512, 0, stream>>>(
        uEf, uEpkH, uEpkL, SpkH, SpkL, WuEh, WuEl, w0uE, wluE, eub,
        hEf, hEf, hEpkH, hEpkL, rb,
        x, (t + 1 < TLEN) ? (t + 1) : -1, nullptr, nullptr, nullptr, 0);
  }

  // ---- attention + decoder init ----
  attn2<<<64, 128, 0, stream>>>(hEf, Wq, Mem, hDf, hDpkH, hDpkL);

  // ---- decoder ----
  for (int t = 0; t < TLEN; ++t) {
    fused_step<97, 96, 104, 192, 3, 7, 0><<<256, 512, 0, stream>>>(
        hDf, hDpkH, hDpkL, SpkH, SpkL, WgDh, WgDl, w0gD, wlgD, dgb,
        hDf, uDf, uDpkH, uDpkL, rb, nullptr, -1, nullptr, nullptr, nullptr, 0);
    fused_step<97, 96, 104, 96, 3, 7, 2><<<256, 512, 0, stream>>>(
        uDf, uDpkH, uDpkL, SpkH, SpkL, WuDh, WuDl, w0uD, wluD, dub,
        hDf, hDf, hDpkH, hDpkL, rb,
        nullptr, -1, pw, pb, out, t);
  }
}